// Round 11
// baseline (882.297 us; speedup 1.0000x reference)
//
#include <hip/hip_runtime.h>
#include <stdint.h>

typedef unsigned short u16;
typedef unsigned int   u32;
typedef short s16x8 __attribute__((ext_vector_type(8)));
typedef u16   u16x8 __attribute__((ext_vector_type(8)));
typedef u32   u32x4 __attribute__((ext_vector_type(4)));
typedef float f32x4 __attribute__((ext_vector_type(4)));
typedef float f32x16 __attribute__((ext_vector_type(16)));

__device__ __forceinline__ u16 f2bf(float f) {
    u32 u = __float_as_uint(f);
    u32 r = u + 0x7fffu + ((u >> 16) & 1u);   // RNE
    return (u16)(r >> 16);
}
__device__ __forceinline__ float bf2f(u16 h) {
    return __uint_as_float(((u32)h) << 16);
}

// pack 2 f32 -> 2 bf16 (RNE), low word = a
__device__ __forceinline__ u32 cvtpk(float a, float b) {
    u32 r;
    asm("v_cvt_pk_bf16_f32 %0, %1, %2" : "=v"(r) : "v"(a), "v"(b));
    return r;
}
// swap a.lanes[32:63] <-> b.lanes[0:31]
__device__ __forceinline__ void swap32(u32& a, u32& b) {
#if __has_builtin(__builtin_amdgcn_permlane32_swap)
    auto r = __builtin_amdgcn_permlane32_swap(a, b, false, false);
    a = r[0]; b = r[1];
#else
    asm volatile("v_permlane32_swap_b32 %0, %1" : "+v"(a), "+v"(b));
#endif
}
// swap a's odd 16-rows <-> b's even 16-rows
__device__ __forceinline__ void swap16(u32& a, u32& b) {
#if __has_builtin(__builtin_amdgcn_permlane16_swap)
    auto r = __builtin_amdgcn_permlane16_swap(a, b, false, false);
    a = r[0]; b = r[1];
#else
    asm volatile("v_permlane16_swap_b32 %0, %1" : "+v"(a), "+v"(b));
#endif
}

// async global->LDS, 16B per lane. LDS dest = wave-uniform base + lane*16.
#define GLD16(gp, lp) __builtin_amdgcn_global_load_lds(                          \
    (const __attribute__((address_space(1))) void*)(uintptr_t)(gp),             \
    (__attribute__((address_space(3))) void*)(u32)(uintptr_t)(lp), 16, 0, 0)

#define FENCE asm volatile("" ::: "memory")

template<int N> __device__ __forceinline__ void waitv() {
    if constexpr (N == 0)       asm volatile("s_waitcnt vmcnt(0)" ::: "memory");
    else if constexpr (N == 2)  asm volatile("s_waitcnt vmcnt(2)" ::: "memory");
    else if constexpr (N == 3)  asm volatile("s_waitcnt vmcnt(3)" ::: "memory");
    else if constexpr (N == 16) asm volatile("s_waitcnt vmcnt(16)" ::: "memory");
    else                        asm volatile("s_waitcnt vmcnt(4)" ::: "memory");
}

// ---------------------------------------------------------------------------
// fp32 -> bf16 weight cast, 8 elems/thread
// ---------------------------------------------------------------------------
__global__ __launch_bounds__(256)
void cast_w(const float* __restrict__ in, u16* __restrict__ out, int n)
{
    const int i = (blockIdx.x * 256 + threadIdx.x) * 8;
    if (i >= n) return;
    f32x4 a = *(const f32x4*)(in + i);
    f32x4 b = *(const f32x4*)(in + i + 4);
    u16x8 o;
    o[0] = f2bf(a[0]); o[1] = f2bf(a[1]); o[2] = f2bf(a[2]); o[3] = f2bf(a[3]);
    o[4] = f2bf(b[0]); o[5] = f2bf(b[1]); o[6] = f2bf(b[2]); o[7] = f2bf(b[3]);
    *(u16x8*)(out + i) = o;
}

// ---------------------------------------------------------------------------
// RMSNorm: one block per row (C=2048), fp32 in -> bf16 out
// ---------------------------------------------------------------------------
__global__ __launch_bounds__(256)
void rmsnorm_k(const float* __restrict__ x, const float* __restrict__ wln,
               u16* __restrict__ out, int C)
{
    const int row = blockIdx.x;
    const int tid = threadIdx.x;
    const float* xr = x + (size_t)row * C;
    f32x4 a = *(const f32x4*)(xr + tid * 8);
    f32x4 b = *(const f32x4*)(xr + tid * 8 + 4);
    float s = a[0]*a[0] + a[1]*a[1] + a[2]*a[2] + a[3]*a[3]
            + b[0]*b[0] + b[1]*b[1] + b[2]*b[2] + b[3]*b[3];
    #pragma unroll
    for (int off = 1; off < 64; off <<= 1) s += __shfl_xor(s, off);
    __shared__ float red[4];
    if ((tid & 63) == 0) red[tid >> 6] = s;
    __syncthreads();
    float tot = red[0] + red[1] + red[2] + red[3];
    float inv = rsqrtf(tot / (float)C + 1e-6f);
    f32x4 wa = *(const f32x4*)(wln + tid * 8);
    f32x4 wb = *(const f32x4*)(wln + tid * 8 + 4);
    u16x8 o;
    o[0] = f2bf(a[0]*inv*wa[0]); o[1] = f2bf(a[1]*inv*wa[1]);
    o[2] = f2bf(a[2]*inv*wa[2]); o[3] = f2bf(a[3]*inv*wa[3]);
    o[4] = f2bf(b[0]*inv*wb[0]); o[5] = f2bf(b[1]*inv*wb[1]);
    o[6] = f2bf(b[2]*inv*wb[2]); o[7] = f2bf(b[3]*inv*wb[3]);
    *(u16x8*)(out + (size_t)row * C + tid * 8) = o;
}

// ---------------------------------------------------------------------------
// gemm32 (R11): 256x256 tile, 4 waves (2x2) of 128x128, mfma_f32_32x32x16,
// BK=64, 2-buffer LDS (128KB), 1 wave/SIMD (acc=256 AGPR).
// NO lockstep phases: per K-tile {32 ds_read; 32 MFMA; lgkm0+barrier;
// stage(t+2) into freed buf; 32 MFMA; vmcnt(16)+barrier}. Intra-wave ILP
// interleaves ds_read with MFMA; LDS/CU drops to 128 reads/K-tile (square
// wave tile) -> MFMA-bound (2070 cyc floor vs LDS 1536).
// Fragment layouts: A/B row=lane&31, k=(lane>>5)*8+e; C/D col=lane&31,
// row=(reg&3)+8*(reg>>2)+4*(lane>>5)  [guide m74/m101].
// MODE 0: bf16   2: fp32 resid+acc   3: bf16 silu(aux)*acc
// MODE 4: QK split -- col<2048 -> Cout (bf16*scale), else aux (bf16)
// ---------------------------------------------------------------------------
template<int MODE>
__global__ __launch_bounds__(256, 1)
void gemm32(const u16* __restrict__ A, const u16* __restrict__ W,
            const float* __restrict__ resid, const u16* __restrict__ aux,
            void* __restrict__ Cout, int M, int N, int K, float scale)
{
    __shared__ __align__(16) u16 lds[2][512 * 64];   // 2 x 64KB (A 256x64 | B 256x64)

    const int tid  = threadIdx.x;
    const int lane = tid & 63;
    const int w    = tid >> 6;          // 0..3
    const int wm   = w >> 1;
    const int wn   = w & 1;

    const int gx  = N >> 8;
    const int nwg = gridDim.x;
    const int sid = ((int)blockIdx.x & 7) * (nwg >> 3) + ((int)blockIdx.x >> 3);
    const int brow = (sid / gx) * 256;
    const int bcol = (sid % gx) * 256;

    const int KT = K >> 6;

    f32x16 acc[4][4] = {};

    // stage full K-tile: A 256x64 + B 256x64; linear LDS dest, pre-swizzled src
    auto stage = [&](int buf, int kt) {
        #pragma unroll
        for (int j = 0; j < 8; ++j) {
            const int row = j * 32 + (tid >> 3);
            const int ch  = (tid & 7) ^ (row & 7);
            GLD16(A + (size_t)(brow + row) * K + kt * 64 + ch * 8,
                  &lds[buf][0] + (j * 32 + w * 8) * 64);
        }
        #pragma unroll
        for (int j = 0; j < 8; ++j) {
            const int row = j * 32 + (tid >> 3);
            const int ch  = (tid & 7) ^ (row & 7);
            GLD16(W + (size_t)(bcol + row) * K + kt * 64 + ch * 8,
                  &lds[buf][512 * 32] + (j * 32 + w * 8) * 64);
        }
    };

    // prologue: tiles 0,1 staged; wait tile0
    stage(0, 0);
    stage(1, 1);
    waitv<16>();
    FENCE; __builtin_amdgcn_s_barrier(); FENCE;

    for (int t = 0; t < KT; ++t) {
        const int cur = t & 1;
        const u16* Ab = &lds[cur][0];
        const u16* Bb = &lds[cur][512 * 32];

        s16x8 af[4][4], bq[4][4];
        #pragma unroll
        for (int i = 0; i < 4; ++i)
            #pragma unroll
            for (int ks = 0; ks < 4; ++ks) {
                const int row = wm * 128 + i * 32 + (lane & 31);
                const int ch  = (ks * 2 + (lane >> 5)) ^ (row & 7);
                af[i][ks] = *(const s16x8*)(Ab + row * 64 + ch * 8);
            }
        #pragma unroll
        for (int j = 0; j < 4; ++j)
            #pragma unroll
            for (int ks = 0; ks < 4; ++ks) {
                const int row = wn * 128 + j * 32 + (lane & 31);
                const int ch  = (ks * 2 + (lane >> 5)) ^ (row & 7);
                bq[j][ks] = *(const s16x8*)(Bb + row * 64 + ch * 8);
            }

        // first half: j = 0,1
        __builtin_amdgcn_s_setprio(1);
        #pragma unroll
        for (int i = 0; i < 4; ++i)
            #pragma unroll
            for (int j = 0; j < 2; ++j)
                #pragma unroll
                for (int ks = 0; ks < 4; ++ks)
                    acc[i][j] = __builtin_amdgcn_mfma_f32_32x32x16_bf16(
                        af[i][ks], bq[j][ks], acc[i][j], 0, 0, 0);
        __builtin_amdgcn_s_setprio(0);

        // all my reads retired; barrier => ALL waves done reading buf[cur]
        asm volatile("s_waitcnt lgkmcnt(0)" ::: "memory");
        FENCE; __builtin_amdgcn_s_barrier(); FENCE;
        if (t + 2 < KT) stage(cur, t + 2);

        // second half: j = 2,3
        __builtin_amdgcn_s_setprio(1);
        #pragma unroll
        for (int i = 0; i < 4; ++i)
            #pragma unroll
            for (int j = 2; j < 4; ++j)
                #pragma unroll
                for (int ks = 0; ks < 4; ++ks)
                    acc[i][j] = __builtin_amdgcn_mfma_f32_32x32x16_bf16(
                        af[i][ks], bq[j][ks], acc[i][j], 0, 0, 0);
        __builtin_amdgcn_s_setprio(0);

        if (t + 1 < KT) {
            if (t + 2 < KT) waitv<16>(); else waitv<0>();   // tile t+1 landed
            FENCE; __builtin_amdgcn_s_barrier(); FENCE;
        }
    }

    // epilogue: C/D col=lane&31, row=(r&3)+8*(r>>2)+4*(lane>>5)
    const int cl = lane & 31;
    const int rh = 4 * (lane >> 5);
    #pragma unroll
    for (int i = 0; i < 4; ++i) {
        #pragma unroll
        for (int j = 0; j < 4; ++j) {
            #pragma unroll
            for (int r = 0; r < 16; ++r) {
                const int row = brow + wm * 128 + i * 32 + (r & 3) + 8 * (r >> 2) + rh;
                const int col = bcol + wn * 128 + j * 32 + cl;
                const float va = acc[i][j][r];
                if (MODE == 0) {
                    ((u16*)Cout)[(size_t)row * N + col] = f2bf(va);
                } else if (MODE == 2) {
                    const size_t idx = (size_t)row * N + col;
                    ((float*)Cout)[idx] = resid[idx] + va;
                } else if (MODE == 3) {
                    const size_t idx = (size_t)row * N + col;
                    const float g  = bf2f(aux[idx]);
                    const float sg = g / (1.0f + exp2f(-g * 1.4426950408889634f));
                    ((u16*)Cout)[idx] = f2bf(sg * va);
                } else {  // MODE 4: fused QK split (N=4096)
                    if (col < 2048)
                        ((u16*)Cout)[(size_t)row * 2048 + col] = f2bf(va * scale);
                    else
                        ((u16*)aux)[(size_t)row * 2048 + (col - 2048)] = f2bf(va);
                }
            }
        }
    }
}

// ---------------------------------------------------------------------------
// 8-phase GEMM (R10 pipelined, measured 145us MLP): C = A @ W^T.
// Used for V^T, O, down (grids where 256^2 tiles would underfill the GPU).
// MODE 0: bf16  1: bf16*scale  2: fp32 resid+acc  3: bf16 silu(aux)*acc
// ---------------------------------------------------------------------------
template<int MODE, int MR>
__global__ __launch_bounds__(512, 1)
void gemm8(const u16* __restrict__ A, const u16* __restrict__ W,
           const float* __restrict__ resid, const u16* __restrict__ aux,
           void* __restrict__ Cout, int M, int N, int K, float scale)
{
    constexpr int BM  = MR * 32;
    constexpr int MR2 = MR / 2;
    constexpr int SRA = MR * 8;
    constexpr int AL  = BM / 128;
    __shared__ __align__(16) u16 lds[2][(BM + 256) * 64];

    const int tid  = threadIdx.x;
    const int lane = tid & 63;
    const int w    = tid >> 6;
    const int wm   = w >> 2;
    const int wn   = w & 3;

    const int gx  = N >> 8;
    const int nwg = gridDim.x;
    const int sid = ((int)blockIdx.x & 7) * (nwg >> 3) + ((int)blockIdx.x >> 3);
    const int brow = (sid / gx) * BM;
    const int bcol = (sid % gx) * 256;

    const int KT = K >> 6;
    const int NI = KT >> 1;

    f32x4 acc[MR][4] = {};

    auto stageA = [&](int buf, int g, int kt) {
        #pragma unroll
        for (int j = 0; j < AL; ++j) {
            const int p   = j * 64 + (tid >> 3);
            const int row = ((p & ~(SRA - 1)) << 1) | (g * SRA) | (p & (SRA - 1));
            const int ch  = (tid & 7) ^ (row & 7);
            const u16* src = A + (size_t)(brow + row) * K + kt * 64 + ch * 8;
            const int p0  = j * 64 + (w << 3);
            const int r0  = ((p0 & ~(SRA - 1)) << 1) | (g * SRA) | (p0 & (SRA - 1));
            GLD16(src, &lds[buf][0] + r0 * 64);
        }
    };
    auto stageB = [&](int buf, int g, int kt) {
        #pragma unroll
        for (int j = 0; j < 2; ++j) {
            const int p   = j * 64 + (tid >> 3);
            const int row = ((p & ~31) << 1) | (g * 32) | (p & 31);
            const int ch  = (tid & 7) ^ (row & 7);
            const u16* src = W + (size_t)(bcol + row) * K + kt * 64 + ch * 8;
            const int p0  = j * 64 + (w << 3);
            const int r0  = ((p0 & ~31) << 1) | (g * 32) | (p0 & 31);
            GLD16(src, &lds[buf][BM * 64] + r0 * 64);
        }
    };

#define LDAF(AF, MH, BUF)                                                        \
    _Pragma("unroll") for (int f = 0; f < MR2; ++f)                              \
    _Pragma("unroll") for (int ks = 0; ks < 2; ++ks) {                           \
        const int row = wm * (BM / 2) + (MH) * (BM / 4) + f * 16 + (lane & 15);  \
        const int ch  = (ks * 4 + (lane >> 4)) ^ (row & 7);                      \
        AF[f][ks] = *(const s16x8*)(&lds[BUF][0] + row * 64 + ch * 8);           \
    }
#define LDBF(BQ, NH, BUF)                                                        \
    _Pragma("unroll") for (int g = 0; g < 2; ++g)                                \
    _Pragma("unroll") for (int ks = 0; ks < 2; ++ks) {                           \
        const int row = wn * 64 + (NH) * 32 + g * 16 + (lane & 15);              \
        const int ch  = (ks * 4 + (lane >> 4)) ^ (row & 7);                      \
        BQ[g][ks] = *(const s16x8*)(&lds[BUF][BM * 64] + row * 64 + ch * 8);     \
    }
#define MFQ(AF, BQ, MH, NH)                                                      \
    __builtin_amdgcn_s_setprio(1);                                               \
    _Pragma("unroll") for (int f = 0; f < MR2; ++f)                              \
    _Pragma("unroll") for (int g = 0; g < 2; ++g)                                \
    _Pragma("unroll") for (int ks = 0; ks < 2; ++ks)                             \
        acc[(MH) * MR2 + f][(NH) * 2 + g] =                                      \
            __builtin_amdgcn_mfma_f32_16x16x32_bf16(                             \
                AF[f][ks], BQ[g][ks], acc[(MH) * MR2 + f][(NH) * 2 + g], 0, 0, 0); \
    __builtin_amdgcn_s_setprio(0);
#define PH_ENTRY FENCE; __builtin_amdgcn_s_barrier();                            \
    asm volatile("s_waitcnt lgkmcnt(0)" ::: "memory"); FENCE

    s16x8 af[MR2][2], bqA[2][2], bqB[2][2];

    stageB(0, 0, 0); stageA(0, 0, 0); stageB(0, 1, 0); stageA(0, 1, 0);
    stageB(1, 0, 1); stageA(1, 0, 1); stageB(1, 1, 1);
    waitv<0>();
    FENCE; __builtin_amdgcn_s_barrier(); FENCE;
    LDAF(af, 0, 0) LDBF(bqA, 0, 0)

    for (int it = 0; it < NI; ++it) {
        const int t1  = 2 * it + 1;
        const int t0n = 2 * it + 2;
        const int t1n = 2 * it + 3;
        const bool last = (it == NI - 1);

        PH_ENTRY; MFQ(af, bqA, 0, 0)
        LDBF(bqB, 1, 0)
        stageA(1, 1, t1);
        PH_ENTRY; MFQ(af, bqB, 0, 1)
        LDAF(af, 1, 0)
        if (!last) stageB(0, 0, t0n);
        PH_ENTRY; MFQ(af, bqB, 1, 1)
        if (!last) stageA(0, 0, t0n);
        PH_ENTRY; MFQ(af, bqA, 1, 0)
        if (!last) stageB(0, 1, t0n);
        if (last) { waitv<0>(); } else { waitv<2>(); }
        LDAF(af, 0, 1) LDBF(bqA, 0, 1)
        PH_ENTRY; MFQ(af, bqA, 0, 0)
        LDBF(bqB, 1, 1)
        if (!last) stageA(0, 1, t0n);
        PH_ENTRY; MFQ(af, bqB, 0, 1)
        LDAF(af, 1, 1)
        if (!last) stageB(1, 0, t1n);
        PH_ENTRY; MFQ(af, bqB, 1, 1)
        if (!last) stageA(1, 0, t1n);
        PH_ENTRY; MFQ(af, bqA, 1, 0)
        if (!last) {
            stageB(1, 1, t1n);
            waitv<2>();
            LDAF(af, 0, 0) LDBF(bqA, 0, 0)
        }
    }
#undef LDAF
#undef LDBF
#undef MFQ
#undef PH_ENTRY

    const int er = (lane >> 4) * 4;
    const int ec = lane & 15;
    #pragma unroll
    for (int i = 0; i < MR; ++i) {
        #pragma unroll
        for (int j = 0; j < 4; ++j) {
            #pragma unroll
            for (int r = 0; r < 4; ++r) {
                const int row = brow + wm * (BM / 2) + i * 16 + er + r;
                const int col = bcol + wn * 64 + j * 16 + ec;
                const size_t idx = (size_t)row * N + col;
                const float va = acc[i][j][r];
                if (MODE == 0)      ((u16*)Cout)[idx] = f2bf(va);
                else if (MODE == 1) ((u16*)Cout)[idx] = f2bf(va * scale);
                else if (MODE == 2) ((float*)Cout)[idx] = resid[idx] + va;
                else {
                    const float g  = bf2f(aux[idx]);
                    const float sg = g / (1.0f + exp2f(-g * 1.4426950408889634f));
                    ((u16*)Cout)[idx] = f2bf(sg * va);
                }
            }
        }
    }
}

// ---------------------------------------------------------------------------
// Flash attention fwd (R9 structure, unchanged): 4 waves x 32 q-rows = 128
// q-rows/block, 512 blocks = 2 blocks/CU; T12 swapped-QK^T in-register
// softmax, T13 defer-max, T14 async-stage, XOR-swizzled K/V dbuf.
// q,k,o: [b][t][h*128+d] bf16.  v PRE-TRANSPOSED: [h*128+d][b*2048+t].
// ---------------------------------------------------------------------------
__global__ __launch_bounds__(256, 2)
void flash_attn(const u16* __restrict__ q, const u16* __restrict__ k,
                const u16* __restrict__ vT, u16* __restrict__ o)
{
    __shared__ __align__(16) u16 Kt[2][64 * 128];
    __shared__ __align__(16) u16 Vt[2][128 * 64];
    const int tid  = threadIdx.x;
    const int lane = tid & 63;
    const int w    = tid >> 6;
    const int qtile = blockIdx.x;
    const int bh    = blockIdx.y;
    const int b = bh >> 4, h = bh & 15;
    const size_t head  = ((size_t)b * 2048) * 2048 + (size_t)h * 128;
    const size_t vbase = ((size_t)h * 128) * 4096 + (size_t)b * 2048;

    s16x8 qf[2][4];
    #pragma unroll
    for (int qi = 0; qi < 2; ++qi) {
        const int tq = qtile * 128 + w * 32 + qi * 16 + (lane & 15);
        const u16* qp = q + head + (size_t)tq * 2048 + (lane >> 4) * 8;
        #pragma unroll
        for (int dk = 0; dk < 4; ++dk) qf[qi][dk] = *(const s16x8*)(qp + dk * 32);
    }

    f32x4 oa[2][8] = {};
    float m_r[2] = {-1e30f, -1e30f};
    float l_r[2] = {0.f, 0.f};

    const int krow = tid >> 2;
    const int kc0  = (tid & 3) * 32;
    const int vd   = tid >> 1;
    const int vk0  = (tid & 1) * 32;
    const u16* kg = k + head + (size_t)krow * 2048 + kc0;
    const u16* vg = vT + vbase + (size_t)vd * 4096 + vk0;
    u32 kwo[4], vwo[4];
    #pragma unroll
    for (int c = 0; c < 4; ++c) {
        kwo[c] = (u32)((krow * 256 + (kc0 + c * 8) * 2) ^ ((krow & 7) << 4));
        vwo[c] = (u32)((vd * 128 + (vk0 + c * 8) * 2)   ^ ((vd & 7) << 4));
    }

    s16x8 kr[4], vr[4];
    #pragma unroll
    for (int c = 0; c < 4; ++c) {
        kr[c] = *(const s16x8*)(kg + c * 8);
        vr[c] = *(const s16x8*)(vg + c * 8);
    }

    for (int kb = 0; kb < 32; ++kb) {
        const int cur = kb & 1;
        char* KtB = (char*)&Kt[cur][0];
        char* VtB = (char*)&Vt[cur][0];
        #pragma unroll
        for (int c = 0; c < 4; ++c) {
            *(s16x8*)(KtB + kwo[c]) = kr[c];
            *(s16x8*)(VtB + vwo[c]) = vr[c];
        }
        if (kb + 1 < 32) {
            const int k0n = (kb + 1) * 64;
            #pragma unroll
            for (int c = 0; c < 4; ++c) {
                kr[c] = *(const s16x8*)(kg + (size_t)k0n * 2048 + c * 8);
                vr[c] = *(const s16x8*)(vg + k0n + c * 8);
            }
        }
        asm volatile("s_waitcnt lgkmcnt(0)" ::: "memory");
        __builtin_amdgcn_s_barrier();
        FENCE;

        f32x4 st[2][4] = {};
        __builtin_amdgcn_s_setprio(1);
        #pragma unroll
        for (int kt = 0; kt < 4; ++kt) {
            const int row = kt * 16 + (lane & 15);
            s16x8 kf[4];
            #pragma unroll
            for (int dk = 0; dk < 4; ++dk) {
                const int dcol = dk * 32 + (lane >> 4) * 8;
                kf[dk] = *(const s16x8*)(KtB + ((row * 256 + dcol * 2) ^ ((row & 7) << 4)));
            }
            #pragma unroll
            for (int qi = 0; qi < 2; ++qi)
                #pragma unroll
                for (int dk = 0; dk < 4; ++dk)
                    st[qi][kt] = __builtin_amdgcn_mfma_f32_16x16x32_bf16(kf[dk], qf[qi][dk], st[qi][kt], 0, 0, 0);
        }
        __builtin_amdgcn_s_setprio(0);

        float mx[2];
        #pragma unroll
        for (int qi = 0; qi < 2; ++qi) {
            float m0 = fmaxf(fmaxf(st[qi][0][0], st[qi][0][1]), fmaxf(st[qi][0][2], st[qi][0][3]));
            float m1 = fmaxf(fmaxf(st[qi][1][0], st[qi][1][1]), fmaxf(st[qi][1][2], st[qi][1][3]));
            float m2 = fmaxf(fmaxf(st[qi][2][0], st[qi][2][1]), fmaxf(st[qi][2][2], st[qi][2][3]));
            float m3 = fmaxf(fmaxf(st[qi][3][0], st[qi][3][1]), fmaxf(st[qi][3][2], st[qi][3][3]));
            float m0123 = fmaxf(fmaxf(m0, m1), fmaxf(m2, m3));
            m0123 = fmaxf(m0123, __shfl_xor(m0123, 16));
            m0123 = fmaxf(m0123, __shfl_xor(m0123, 32));
            mx[qi] = m0123;
        }
        const bool grow = (mx[0] > m_r[0] + 8.f) || (mx[1] > m_r[1] + 8.f);
        if (__any(grow)) {
            #pragma unroll
            for (int qi = 0; qi < 2; ++qi) {
                const float mn = fmaxf(m_r[qi], mx[qi]);
                const float sc = exp2f(m_r[qi] - mn);
                m_r[qi] = mn;
                l_r[qi] *= sc;
                const float s0 = __shfl(sc, (lane >> 4) * 4 + 0);
                const float s1 = __shfl(sc, (lane >> 4) * 4 + 1);
                const float s2 = __shfl(sc, (lane >> 4) * 4 + 2);
                const float s3 = __shfl(sc, (lane >> 4) * 4 + 3);
                #pragma unroll
                for (int ni = 0; ni < 8; ++ni) {
                    oa[qi][ni][0] *= s0; oa[qi][ni][1] *= s1;
                    oa[qi][ni][2] *= s2; oa[qi][ni][3] *= s3;
                }
            }
        }

        s16x8 pa[2][2];
        #pragma unroll
        for (int qi = 0; qi < 2; ++qi) {
            float sum = 0.f;
            #pragma unroll
            for (int kt = 0; kt < 4; ++kt)
                #pragma unroll
                for (int r = 0; r < 4; ++r) {
                    const float p = exp2f(st[qi][kt][r] - m_r[qi]);
                    st[qi][kt][r] = p;
                    sum += p;
                }
            sum += __shfl_xor(sum, 16);
            sum += __shfl_xor(sum, 32);
            l_r[qi] += sum;

            u32 q01[4], q23[4];
            #pragma unroll
            for (int kt = 0; kt < 4; ++kt) {
                q01[kt] = cvtpk(st[qi][kt][0], st[qi][kt][1]);
                q23[kt] = cvtpk(st[qi][kt][2], st[qi][kt][3]);
            }
            #pragma unroll
            for (int ks = 0; ks < 2; ++ks) {
                u32 X = q01[2 * ks], Y = q01[2 * ks + 1];
                swap32(X, Y); swap16(X, Y);
                u32 U = q23[2 * ks], V = q23[2 * ks + 1];
                swap32(U, V); swap16(U, V);
                u32x4 t; t[0] = X; t[1] = U; t[2] = Y; t[3] = V;
                pa[qi][ks] = __builtin_bit_cast(s16x8, t);
            }
        }

        __builtin_amdgcn_s_setprio(1);
        #pragma unroll
        for (int ks = 0; ks < 2; ++ks) {
            const int keyb = ks * 32 + (lane >> 4) * 8;
            #pragma unroll
            for (int ni = 0; ni < 8; ++ni) {
                const int dd = ni * 16 + (lane & 15);
                s16x8 vf = *(const s16x8*)(VtB + ((dd * 128 + keyb * 2) ^ ((dd & 7) << 4)));
                #pragma unroll
                for (int qi = 0; qi < 2; ++qi)
                    oa[qi][ni] = __builtin_amdgcn_mfma_f32_16x16x32_bf16(pa[qi][ks], vf, oa[qi][ni], 0, 0, 0);
            }
        }
        __builtin_amdgcn_s_setprio(0);
    }
    #pragma unroll
    for (int qi = 0; qi < 2; ++qi) {
        #pragma unroll
        for (int r = 0; r < 4; ++r) {
            const float inv = 1.0f / __shfl(l_r[qi], (lane >> 4) * 4 + r);
            const int tout = qtile * 128 + w * 32 + qi * 16 + (lane >> 4) * 4 + r;
            u16* op = o + head + (size_t)tout * 2048 + (lane & 15);
            #pragma unroll
            for (int ni = 0; ni < 8; ++ni)
                op[ni * 16] = f2bf(oa[qi][ni][r] * inv);
        }
    }
}

// ---------------------------------------------------------------------------
extern "C" void kernel_launch(void* const* d_in, const int* in_sizes, int n_in,
                              void* d_out, int out_size, void* d_ws, size_t ws_size,
                              hipStream_t stream)
{
    (void)in_sizes; (void)n_in; (void)out_size; (void)ws_size;
    const float* x    = (const float*)d_in[0];
    const float* wln1 = (const float*)d_in[1];
    const float* wq   = (const float*)d_in[2];
    const float* wk   = (const float*)d_in[3];
    const float* wv   = (const float*)d_in[4];
    const float* wo   = (const float*)d_in[5];
    const float* wln2 = (const float*)d_in[6];
    const float* wg   = (const float*)d_in[7];
    const float* wu   = (const float*)d_in[8];
    const float* wd   = (const float*)d_in[9];
    float* out = (float*)d_out;

    const size_t MB = 1024ull * 1024ull;
    char* ws = (char*)d_ws;
    u16*   arena = (u16*)(ws + 0);          // 32 MB: bf16 weight arena (reused)
    float* hbuf  = (float*)(ws + 32 * MB);  // 32 MB: x + attn residual (fp32)
    u16*   xn    = (u16*)(ws + 64 * MB);    // 16 MB: rmsnorm output (bf16)
    u16*   qb    = (u16*)(ws + 80 * MB);    // 16 MB
    u16*   kbuf  = (u16*)(ws + 96 * MB);    // 16 MB
    u16*   vT    = (u16*)(ws + 112 * MB);   // 16 MB: V transposed [h*128+d][b*2048+t]
    u16*   abuf  = (u16*)(ws + 128 * MB);   // 16 MB (ends 144 MB)
    u16*   gbuf  = (u16*)(ws + 80 * MB);    // 64 MB, aliases q..attn (dead then)

    const int M = 4096, C = 2048, I = 8192;
    const float qscale = 0.1275164899f;     // (1/sqrt(128)) * log2(e)
    dim3 blk(256);
    dim3 blk8(512);

    rmsnorm_k<<<M, blk, 0, stream>>>(x, wln1, xn, C);

    // fused Q+K: arena = [wq ; wk] (4096 x 2048), one 256^2 gemm32, split epi
    cast_w<<<(C * C) / 2048, blk, 0, stream>>>(wq, arena, C * C);
    cast_w<<<(C * C) / 2048, blk, 0, stream>>>(wk, arena + (size_t)C * C, C * C);
    gemm32<4><<<dim3((2 * C / 256) * (M / 256)), blk, 0, stream>>>(
        xn, arena, nullptr, kbuf, qb, M, 2 * C, C, qscale);

    cast_w<<<(C * C) / 2048, blk, 0, stream>>>(wv, arena, C * C);
    // V^T = Wv @ Xn^T : operand-swapped GEMM -> coalesced transposed output
    gemm8<0, 4><<<dim3((M / 256) * (C / 128)), blk8, 0, stream>>>(arena, xn, nullptr, nullptr, vT, C, M, C, 1.f);

    flash_attn<<<dim3(2048 / 128, 32), blk, 0, stream>>>(qb, kbuf, vT, abuf);

    cast_w<<<(C * C) / 2048, blk, 0, stream>>>(wo, arena, C * C);
    gemm8<2, 4><<<dim3((C / 256) * (M / 128)), blk8, 0, stream>>>(abuf, arena, x, nullptr, hbuf, M, C, C, 1.f);

    rmsnorm_k<<<M, blk, 0, stream>>>(hbuf, wln2, xn, C);

    cast_w<<<(I * C) / 2048, blk, 0, stream>>>(wg, arena, I * C);
    gemm32<0><<<dim3((I / 256) * (M / 256)), blk, 0, stream>>>(xn, arena, nullptr, nullptr, gbuf, M, I, C, 1.f);
    cast_w<<<(I * C) / 2048, blk, 0, stream>>>(wu, arena, I * C);
    gemm32<3><<<dim3((I / 256) * (M / 256)), blk, 0, stream>>>(xn, arena, nullptr, gbuf, gbuf, M, I, C, 1.f);
    cast_w<<<(C * I) / 2048, blk, 0, stream>>>(wd, arena, C * I);
    gemm8<2, 4><<<dim3((C / 256) * (M / 128)), blk8, 0, stream>>>(gbuf, arena, hbuf, nullptr, out, M, C, I, 1.f);
}

// Round 12
// 722.640 us; speedup vs baseline: 1.2209x; 1.2209x over previous
//
#include <hip/hip_runtime.h>
#include <stdint.h>

typedef unsigned short u16;
typedef unsigned int   u32;
typedef short s16x8 __attribute__((ext_vector_type(8)));
typedef u16   u16x8 __attribute__((ext_vector_type(8)));
typedef u32   u32x4 __attribute__((ext_vector_type(4)));
typedef float f32x4 __attribute__((ext_vector_type(4)));

__device__ __forceinline__ u16 f2bf(float f) {
    u32 u = __float_as_uint(f);
    u32 r = u + 0x7fffu + ((u >> 16) & 1u);   // RNE
    return (u16)(r >> 16);
}
__device__ __forceinline__ float bf2f(u16 h) {
    return __uint_as_float(((u32)h) << 16);
}

// pack 2 f32 -> 2 bf16 (RNE), low word = a
__device__ __forceinline__ u32 cvtpk(float a, float b) {
    u32 r;
    asm("v_cvt_pk_bf16_f32 %0, %1, %2" : "=v"(r) : "v"(a), "v"(b));
    return r;
}
// swap a.lanes[32:63] <-> b.lanes[0:31]
__device__ __forceinline__ void swap32(u32& a, u32& b) {
#if __has_builtin(__builtin_amdgcn_permlane32_swap)
    auto r = __builtin_amdgcn_permlane32_swap(a, b, false, false);
    a = r[0]; b = r[1];
#else
    asm volatile("v_permlane32_swap_b32 %0, %1" : "+v"(a), "+v"(b));
#endif
}
// swap a's odd 16-rows <-> b's even 16-rows
__device__ __forceinline__ void swap16(u32& a, u32& b) {
#if __has_builtin(__builtin_amdgcn_permlane16_swap)
    auto r = __builtin_amdgcn_permlane16_swap(a, b, false, false);
    a = r[0]; b = r[1];
#else
    asm volatile("v_permlane16_swap_b32 %0, %1" : "+v"(a), "+v"(b));
#endif
}

// async global->LDS, 16B per lane. LDS dest = wave-uniform base + lane*16.
#define GLD16(gp, lp) __builtin_amdgcn_global_load_lds(                          \
    (const __attribute__((address_space(1))) void*)(uintptr_t)(gp),             \
    (__attribute__((address_space(3))) void*)(u32)(uintptr_t)(lp), 16, 0, 0)

#define FENCE asm volatile("" ::: "memory")

template<int N> __device__ __forceinline__ void waitv() {
    if constexpr (N == 0)      asm volatile("s_waitcnt vmcnt(0)" ::: "memory");
    else if constexpr (N == 2) asm volatile("s_waitcnt vmcnt(2)" ::: "memory");
    else if constexpr (N == 3) asm volatile("s_waitcnt vmcnt(3)" ::: "memory");
    else                       asm volatile("s_waitcnt vmcnt(4)" ::: "memory");
}

// ---------------------------------------------------------------------------
// fp32 -> bf16 weight cast, 8 elems/thread
// ---------------------------------------------------------------------------
__global__ __launch_bounds__(256)
void cast_w(const float* __restrict__ in, u16* __restrict__ out, int n)
{
    const int i = (blockIdx.x * 256 + threadIdx.x) * 8;
    if (i >= n) return;
    f32x4 a = *(const f32x4*)(in + i);
    f32x4 b = *(const f32x4*)(in + i + 4);
    u16x8 o;
    o[0] = f2bf(a[0]); o[1] = f2bf(a[1]); o[2] = f2bf(a[2]); o[3] = f2bf(a[3]);
    o[4] = f2bf(b[0]); o[5] = f2bf(b[1]); o[6] = f2bf(b[2]); o[7] = f2bf(b[3]);
    *(u16x8*)(out + i) = o;
}

// ---------------------------------------------------------------------------
// RMSNorm: one block per row (C=2048), fp32 in -> bf16 out
// ---------------------------------------------------------------------------
__global__ __launch_bounds__(256)
void rmsnorm_k(const float* __restrict__ x, const float* __restrict__ wln,
               u16* __restrict__ out, int C)
{
    const int row = blockIdx.x;
    const int tid = threadIdx.x;
    const float* xr = x + (size_t)row * C;
    f32x4 a = *(const f32x4*)(xr + tid * 8);
    f32x4 b = *(const f32x4*)(xr + tid * 8 + 4);
    float s = a[0]*a[0] + a[1]*a[1] + a[2]*a[2] + a[3]*a[3]
            + b[0]*b[0] + b[1]*b[1] + b[2]*b[2] + b[3]*b[3];
    #pragma unroll
    for (int off = 1; off < 64; off <<= 1) s += __shfl_xor(s, off);
    __shared__ float red[4];
    if ((tid & 63) == 0) red[tid >> 6] = s;
    __syncthreads();
    float tot = red[0] + red[1] + red[2] + red[3];
    float inv = rsqrtf(tot / (float)C + 1e-6f);
    f32x4 wa = *(const f32x4*)(wln + tid * 8);
    f32x4 wb = *(const f32x4*)(wln + tid * 8 + 4);
    u16x8 o;
    o[0] = f2bf(a[0]*inv*wa[0]); o[1] = f2bf(a[1]*inv*wa[1]);
    o[2] = f2bf(a[2]*inv*wa[2]); o[3] = f2bf(a[3]*inv*wa[3]);
    o[4] = f2bf(b[0]*inv*wb[0]); o[5] = f2bf(b[1]*inv*wb[1]);
    o[6] = f2bf(b[2]*inv*wb[2]); o[7] = f2bf(b[3]*inv*wb[3]);
    *(u16x8*)(out + (size_t)row * C + tid * 8) = o;
}

// ---------------------------------------------------------------------------
// Pipelined 8-phase GEMM (R10, measured 145us MLP / 948TF): C = A @ W^T.
// Tile BM x 256, BK=64, 8 waves, Gray-code quadrant walk. Each phase:
//   {barrier; lgkm(0); MFMA (frags read LAST phase); ds_read next frags;
//    stage slot; [vmcnt(2) at P4/P8]}
// MODE 0: bf16  1: bf16*scale  2: fp32 resid+acc  3: bf16 silu(aux)*acc
// MODE 5: QK split -- col<2048 -> Cout bf16*scale, else aux (bf16), N=4096
// ---------------------------------------------------------------------------
template<int MODE, int MR>
__global__ __launch_bounds__(512, 1)
void gemm8(const u16* __restrict__ A, const u16* __restrict__ W,
           const float* __restrict__ resid, const u16* __restrict__ aux,
           void* __restrict__ Cout, int M, int N, int K, float scale)
{
    constexpr int BM  = MR * 32;
    constexpr int MR2 = MR / 2;
    constexpr int SRA = MR * 8;
    constexpr int AL  = BM / 128;
    __shared__ __align__(16) u16 lds[2][(BM + 256) * 64];

    const int tid  = threadIdx.x;
    const int lane = tid & 63;
    const int w    = tid >> 6;
    const int wm   = w >> 2;
    const int wn   = w & 3;

    const int gx  = N >> 8;
    const int nwg = gridDim.x;
    const int sid = ((int)blockIdx.x & 7) * (nwg >> 3) + ((int)blockIdx.x >> 3);
    const int brow = (sid / gx) * BM;
    const int bcol = (sid % gx) * 256;

    const int KT = K >> 6;
    const int NI = KT >> 1;

    f32x4 acc[MR][4] = {};

    auto stageA = [&](int buf, int g, int kt) {
        #pragma unroll
        for (int j = 0; j < AL; ++j) {
            const int p   = j * 64 + (tid >> 3);
            const int row = ((p & ~(SRA - 1)) << 1) | (g * SRA) | (p & (SRA - 1));
            const int ch  = (tid & 7) ^ (row & 7);
            const u16* src = A + (size_t)(brow + row) * K + kt * 64 + ch * 8;
            const int p0  = j * 64 + (w << 3);
            const int r0  = ((p0 & ~(SRA - 1)) << 1) | (g * SRA) | (p0 & (SRA - 1));
            GLD16(src, &lds[buf][0] + r0 * 64);
        }
    };
    auto stageB = [&](int buf, int g, int kt) {
        #pragma unroll
        for (int j = 0; j < 2; ++j) {
            const int p   = j * 64 + (tid >> 3);
            const int row = ((p & ~31) << 1) | (g * 32) | (p & 31);
            const int ch  = (tid & 7) ^ (row & 7);
            const u16* src = W + (size_t)(bcol + row) * K + kt * 64 + ch * 8;
            const int p0  = j * 64 + (w << 3);
            const int r0  = ((p0 & ~31) << 1) | (g * 32) | (p0 & 31);
            GLD16(src, &lds[buf][BM * 64] + r0 * 64);
        }
    };

#define LDAF(AF, MH, BUF)                                                        \
    _Pragma("unroll") for (int f = 0; f < MR2; ++f)                              \
    _Pragma("unroll") for (int ks = 0; ks < 2; ++ks) {                           \
        const int row = wm * (BM / 2) + (MH) * (BM / 4) + f * 16 + (lane & 15);  \
        const int ch  = (ks * 4 + (lane >> 4)) ^ (row & 7);                      \
        AF[f][ks] = *(const s16x8*)(&lds[BUF][0] + row * 64 + ch * 8);           \
    }
#define LDBF(BQ, NH, BUF)                                                        \
    _Pragma("unroll") for (int g = 0; g < 2; ++g)                                \
    _Pragma("unroll") for (int ks = 0; ks < 2; ++ks) {                           \
        const int row = wn * 64 + (NH) * 32 + g * 16 + (lane & 15);              \
        const int ch  = (ks * 4 + (lane >> 4)) ^ (row & 7);                      \
        BQ[g][ks] = *(const s16x8*)(&lds[BUF][BM * 64] + row * 64 + ch * 8);     \
    }
#define MFQ(AF, BQ, MH, NH)                                                      \
    __builtin_amdgcn_s_setprio(1);                                               \
    _Pragma("unroll") for (int f = 0; f < MR2; ++f)                              \
    _Pragma("unroll") for (int g = 0; g < 2; ++g)                                \
    _Pragma("unroll") for (int ks = 0; ks < 2; ++ks)                             \
        acc[(MH) * MR2 + f][(NH) * 2 + g] =                                      \
            __builtin_amdgcn_mfma_f32_16x16x32_bf16(                             \
                AF[f][ks], BQ[g][ks], acc[(MH) * MR2 + f][(NH) * 2 + g], 0, 0, 0); \
    __builtin_amdgcn_s_setprio(0);
#define PH_ENTRY FENCE; __builtin_amdgcn_s_barrier();                            \
    asm volatile("s_waitcnt lgkmcnt(0)" ::: "memory"); FENCE

    s16x8 af[MR2][2], bqA[2][2], bqB[2][2];

    // prologue: t0 full -> buf0; t1's B0,A0,B1 -> buf1 (A1 staged at P1).
    stageB(0, 0, 0); stageA(0, 0, 0); stageB(0, 1, 0); stageA(0, 1, 0);
    stageB(1, 0, 1); stageA(1, 0, 1); stageB(1, 1, 1);
    waitv<0>();
    FENCE; __builtin_amdgcn_s_barrier(); FENCE;
    LDAF(af, 0, 0) LDBF(bqA, 0, 0)

    for (int it = 0; it < NI; ++it) {
        const int t1  = 2 * it + 1;
        const int t0n = 2 * it + 2;
        const int t1n = 2 * it + 3;
        const bool last = (it == NI - 1);

        // P1: Q(0,0) buf0
        PH_ENTRY; MFQ(af, bqA, 0, 0)
        LDBF(bqB, 1, 0)
        stageA(1, 1, t1);
        // P2: Q(0,1) buf0
        PH_ENTRY; MFQ(af, bqB, 0, 1)
        LDAF(af, 1, 0)
        if (!last) stageB(0, 0, t0n);
        // P3: Q(1,1) buf0
        PH_ENTRY; MFQ(af, bqB, 1, 1)
        if (!last) stageA(0, 0, t0n);
        // P4: Q(1,0) buf0 -> buffer switch pre-read
        PH_ENTRY; MFQ(af, bqA, 1, 0)
        if (!last) stageB(0, 1, t0n);
        if (last) { waitv<0>(); } else { waitv<2>(); }
        LDAF(af, 0, 1) LDBF(bqA, 0, 1)
        // P5: Q(0,0) buf1
        PH_ENTRY; MFQ(af, bqA, 0, 0)
        LDBF(bqB, 1, 1)
        if (!last) stageA(0, 1, t0n);
        // P6: Q(0,1) buf1
        PH_ENTRY; MFQ(af, bqB, 0, 1)
        LDAF(af, 1, 1)
        if (!last) stageB(1, 0, t1n);
        // P7: Q(1,1) buf1
        PH_ENTRY; MFQ(af, bqB, 1, 1)
        if (!last) stageA(1, 0, t1n);
        // P8: Q(1,0) buf1 -> buffer switch pre-read (skip on last)
        PH_ENTRY; MFQ(af, bqA, 1, 0)
        if (!last) {
            stageB(1, 1, t1n);
            waitv<2>();
            LDAF(af, 0, 0) LDBF(bqA, 0, 0)
        }
    }
#undef LDAF
#undef LDBF
#undef MFQ
#undef PH_ENTRY

    // epilogue: D layout col=lane&15, row=(lane>>4)*4+r
    const int er = (lane >> 4) * 4;
    const int ec = lane & 15;
    #pragma unroll
    for (int i = 0; i < MR; ++i) {
        #pragma unroll
        for (int j = 0; j < 4; ++j) {
            #pragma unroll
            for (int r = 0; r < 4; ++r) {
                const int row = brow + wm * (BM / 2) + i * 16 + er + r;
                const int col = bcol + wn * 64 + j * 16 + ec;
                const float va = acc[i][j][r];
                if (MODE == 5) {
                    if (col < 2048)
                        ((u16*)Cout)[(size_t)row * 2048 + col] = f2bf(va * scale);
                    else
                        ((u16*)aux)[(size_t)row * 2048 + (col - 2048)] = f2bf(va);
                } else {
                    const size_t idx = (size_t)row * N + col;
                    if (MODE == 0)      ((u16*)Cout)[idx] = f2bf(va);
                    else if (MODE == 1) ((u16*)Cout)[idx] = f2bf(va * scale);
                    else if (MODE == 2) ((float*)Cout)[idx] = resid[idx] + va;
                    else {
                        const float g  = bf2f(aux[idx]);
                        const float sg = g / (1.0f + exp2f(-g * 1.4426950408889634f));
                        ((u16*)Cout)[idx] = f2bf(sg * va);
                    }
                }
            }
        }
    }
}

// ---------------------------------------------------------------------------
// Flash attention fwd (R9/R10 structure): 4 waves x 32 q-rows = 128
// q-rows/block, 512 blocks = 2 blocks/CU; T12 swapped-QK^T in-register
// softmax, T13 defer-max, T14 async-stage, XOR-swizzled K/V dbuf.
// q,k,o: [b][t][h*128+d] bf16.  v PRE-TRANSPOSED: [h*128+d][b*2048+t].
// ---------------------------------------------------------------------------
__global__ __launch_bounds__(256, 2)
void flash_attn(const u16* __restrict__ q, const u16* __restrict__ k,
                const u16* __restrict__ vT, u16* __restrict__ o)
{
    __shared__ __align__(16) u16 Kt[2][64 * 128];
    __shared__ __align__(16) u16 Vt[2][128 * 64];
    const int tid  = threadIdx.x;
    const int lane = tid & 63;
    const int w    = tid >> 6;
    const int qtile = blockIdx.x;
    const int bh    = blockIdx.y;
    const int b = bh >> 4, h = bh & 15;
    const size_t head  = ((size_t)b * 2048) * 2048 + (size_t)h * 128;
    const size_t vbase = ((size_t)h * 128) * 4096 + (size_t)b * 2048;

    s16x8 qf[2][4];
    #pragma unroll
    for (int qi = 0; qi < 2; ++qi) {
        const int tq = qtile * 128 + w * 32 + qi * 16 + (lane & 15);
        const u16* qp = q + head + (size_t)tq * 2048 + (lane >> 4) * 8;
        #pragma unroll
        for (int dk = 0; dk < 4; ++dk) qf[qi][dk] = *(const s16x8*)(qp + dk * 32);
    }

    f32x4 oa[2][8] = {};
    float m_r[2] = {-1e30f, -1e30f};
    float l_r[2] = {0.f, 0.f};

    const int krow = tid >> 2;
    const int kc0  = (tid & 3) * 32;
    const int vd   = tid >> 1;
    const int vk0  = (tid & 1) * 32;
    const u16* kg = k + head + (size_t)krow * 2048 + kc0;
    const u16* vg = vT + vbase + (size_t)vd * 4096 + vk0;
    u32 kwo[4], vwo[4];
    #pragma unroll
    for (int c = 0; c < 4; ++c) {
        kwo[c] = (u32)((krow * 256 + (kc0 + c * 8) * 2) ^ ((krow & 7) << 4));
        vwo[c] = (u32)((vd * 128 + (vk0 + c * 8) * 2)   ^ ((vd & 7) << 4));
    }

    s16x8 kr[4], vr[4];
    #pragma unroll
    for (int c = 0; c < 4; ++c) {
        kr[c] = *(const s16x8*)(kg + c * 8);
        vr[c] = *(const s16x8*)(vg + c * 8);
    }

    for (int kb = 0; kb < 32; ++kb) {
        const int cur = kb & 1;
        char* KtB = (char*)&Kt[cur][0];
        char* VtB = (char*)&Vt[cur][0];
        #pragma unroll
        for (int c = 0; c < 4; ++c) {
            *(s16x8*)(KtB + kwo[c]) = kr[c];
            *(s16x8*)(VtB + vwo[c]) = vr[c];
        }
        if (kb + 1 < 32) {
            const int k0n = (kb + 1) * 64;
            #pragma unroll
            for (int c = 0; c < 4; ++c) {
                kr[c] = *(const s16x8*)(kg + (size_t)k0n * 2048 + c * 8);
                vr[c] = *(const s16x8*)(vg + k0n + c * 8);
            }
        }
        asm volatile("s_waitcnt lgkmcnt(0)" ::: "memory");
        __builtin_amdgcn_s_barrier();
        FENCE;

        f32x4 st[2][4] = {};
        __builtin_amdgcn_s_setprio(1);
        #pragma unroll
        for (int kt = 0; kt < 4; ++kt) {
            const int row = kt * 16 + (lane & 15);
            s16x8 kf[4];
            #pragma unroll
            for (int dk = 0; dk < 4; ++dk) {
                const int dcol = dk * 32 + (lane >> 4) * 8;
                kf[dk] = *(const s16x8*)(KtB + ((row * 256 + dcol * 2) ^ ((row & 7) << 4)));
            }
            #pragma unroll
            for (int qi = 0; qi < 2; ++qi)
                #pragma unroll
                for (int dk = 0; dk < 4; ++dk)
                    st[qi][kt] = __builtin_amdgcn_mfma_f32_16x16x32_bf16(kf[dk], qf[qi][dk], st[qi][kt], 0, 0, 0);
        }
        __builtin_amdgcn_s_setprio(0);

        float mx[2];
        #pragma unroll
        for (int qi = 0; qi < 2; ++qi) {
            float m0 = fmaxf(fmaxf(st[qi][0][0], st[qi][0][1]), fmaxf(st[qi][0][2], st[qi][0][3]));
            float m1 = fmaxf(fmaxf(st[qi][1][0], st[qi][1][1]), fmaxf(st[qi][1][2], st[qi][1][3]));
            float m2 = fmaxf(fmaxf(st[qi][2][0], st[qi][2][1]), fmaxf(st[qi][2][2], st[qi][2][3]));
            float m3 = fmaxf(fmaxf(st[qi][3][0], st[qi][3][1]), fmaxf(st[qi][3][2], st[qi][3][3]));
            float m0123 = fmaxf(fmaxf(m0, m1), fmaxf(m2, m3));
            m0123 = fmaxf(m0123, __shfl_xor(m0123, 16));
            m0123 = fmaxf(m0123, __shfl_xor(m0123, 32));
            mx[qi] = m0123;
        }
        const bool grow = (mx[0] > m_r[0] + 8.f) || (mx[1] > m_r[1] + 8.f);
        if (__any(grow)) {
            #pragma unroll
            for (int qi = 0; qi < 2; ++qi) {
                const float mn = fmaxf(m_r[qi], mx[qi]);
                const float sc = exp2f(m_r[qi] - mn);
                m_r[qi] = mn;
                l_r[qi] *= sc;
                const float s0 = __shfl(sc, (lane >> 4) * 4 + 0);
                const float s1 = __shfl(sc, (lane >> 4) * 4 + 1);
                const float s2 = __shfl(sc, (lane >> 4) * 4 + 2);
                const float s3 = __shfl(sc, (lane >> 4) * 4 + 3);
                #pragma unroll
                for (int ni = 0; ni < 8; ++ni) {
                    oa[qi][ni][0] *= s0; oa[qi][ni][1] *= s1;
                    oa[qi][ni][2] *= s2; oa[qi][ni][3] *= s3;
                }
            }
        }

        s16x8 pa[2][2];
        #pragma unroll
        for (int qi = 0; qi < 2; ++qi) {
            float sum = 0.f;
            #pragma unroll
            for (int kt = 0; kt < 4; ++kt)
                #pragma unroll
                for (int r = 0; r < 4; ++r) {
                    const float p = exp2f(st[qi][kt][r] - m_r[qi]);
                    st[qi][kt][r] = p;
                    sum += p;
                }
            sum += __shfl_xor(sum, 16);
            sum += __shfl_xor(sum, 32);
            l_r[qi] += sum;

            u32 q01[4], q23[4];
            #pragma unroll
            for (int kt = 0; kt < 4; ++kt) {
                q01[kt] = cvtpk(st[qi][kt][0], st[qi][kt][1]);
                q23[kt] = cvtpk(st[qi][kt][2], st[qi][kt][3]);
            }
            #pragma unroll
            for (int ks = 0; ks < 2; ++ks) {
                u32 X = q01[2 * ks], Y = q01[2 * ks + 1];
                swap32(X, Y); swap16(X, Y);
                u32 U = q23[2 * ks], V = q23[2 * ks + 1];
                swap32(U, V); swap16(U, V);
                u32x4 t; t[0] = X; t[1] = U; t[2] = Y; t[3] = V;
                pa[qi][ks] = __builtin_bit_cast(s16x8, t);
            }
        }

        __builtin_amdgcn_s_setprio(1);
        #pragma unroll
        for (int ks = 0; ks < 2; ++ks) {
            const int keyb = ks * 32 + (lane >> 4) * 8;
            #pragma unroll
            for (int ni = 0; ni < 8; ++ni) {
                const int dd = ni * 16 + (lane & 15);
                s16x8 vf = *(const s16x8*)(VtB + ((dd * 128 + keyb * 2) ^ ((dd & 7) << 4)));
                #pragma unroll
                for (int qi = 0; qi < 2; ++qi)
                    oa[qi][ni] = __builtin_amdgcn_mfma_f32_16x16x32_bf16(pa[qi][ks], vf, oa[qi][ni], 0, 0, 0);
            }
        }
        __builtin_amdgcn_s_setprio(0);
    }
    #pragma unroll
    for (int qi = 0; qi < 2; ++qi) {
        #pragma unroll
        for (int r = 0; r < 4; ++r) {
            const float inv = 1.0f / __shfl(l_r[qi], (lane >> 4) * 4 + r);
            const int tout = qtile * 128 + w * 32 + qi * 16 + (lane >> 4) * 4 + r;
            u16* op = o + head + (size_t)tout * 2048 + (lane & 15);
            #pragma unroll
            for (int ni = 0; ni < 8; ++ni)
                op[ni * 16] = f2bf(oa[qi][ni][r] * inv);
        }
    }
}

// ---------------------------------------------------------------------------
extern "C" void kernel_launch(void* const* d_in, const int* in_sizes, int n_in,
                              void* d_out, int out_size, void* d_ws, size_t ws_size,
                              hipStream_t stream)
{
    (void)in_sizes; (void)n_in; (void)out_size; (void)ws_size;
    const float* x    = (const float*)d_in[0];
    const float* wln1 = (const float*)d_in[1];
    const float* wq   = (const float*)d_in[2];
    const float* wk   = (const float*)d_in[3];
    const float* wv   = (const float*)d_in[4];
    const float* wo   = (const float*)d_in[5];
    const float* wln2 = (const float*)d_in[6];
    const float* wg   = (const float*)d_in[7];
    const float* wu   = (const float*)d_in[8];
    const float* wd   = (const float*)d_in[9];
    float* out = (float*)d_out;

    const size_t MB = 1024ull * 1024ull;
    char* ws = (char*)d_ws;
    u16*   arena = (u16*)(ws + 0);          // 32 MB: bf16 weight arena (reused)
    float* hbuf  = (float*)(ws + 32 * MB);  // 32 MB: x + attn residual (fp32)
    u16*   xn    = (u16*)(ws + 64 * MB);    // 16 MB: rmsnorm output (bf16)
    u16*   qb    = (u16*)(ws + 80 * MB);    // 16 MB
    u16*   kbuf  = (u16*)(ws + 96 * MB);    // 16 MB
    u16*   vT    = (u16*)(ws + 112 * MB);   // 16 MB: V transposed [h*128+d][b*2048+t]
    u16*   abuf  = (u16*)(ws + 128 * MB);   // 16 MB (ends 144 MB)
    u16*   gbuf  = (u16*)(ws + 80 * MB);    // 64 MB, aliases q..attn (dead then)

    const int M = 4096, C = 2048, I = 8192;
    const float qscale = 0.1275164899f;     // (1/sqrt(128)) * log2(e)
    dim3 blk(256);
    dim3 blk8(512);

    rmsnorm_k<<<M, blk, 0, stream>>>(x, wln1, xn, C);

    // fused Q+K: arena = [wq ; wk] (4096 x 2048), one gemm8 with split epilogue
    cast_w<<<(C * C) / 2048, blk, 0, stream>>>(wq, arena, C * C);
    cast_w<<<(C * C) / 2048, blk, 0, stream>>>(wk, arena + (size_t)C * C, C * C);
    gemm8<5, 4><<<dim3((2 * C / 256) * (M / 128)), blk8, 0, stream>>>(
        xn, arena, nullptr, kbuf, qb, M, 2 * C, C, qscale);

    cast_w<<<(C * C) / 2048, blk, 0, stream>>>(wv, arena, C * C);
    // V^T = Wv @ Xn^T : operand-swapped GEMM -> coalesced transposed output
    gemm8<0, 4><<<dim3((M / 256) * (C / 128)), blk8, 0, stream>>>(arena, xn, nullptr, nullptr, vT, C, M, C, 1.f);

    flash_attn<<<dim3(2048 / 128, 32), blk, 0, stream>>>(qb, kbuf, vT, abuf);

    cast_w<<<(C * C) / 2048, blk, 0, stream>>>(wo, arena, C * C);
    gemm8<2, 4><<<dim3((C / 256) * (M / 128)), blk8, 0, stream>>>(abuf, arena, x, nullptr, hbuf, M, C, C, 1.f);

    rmsnorm_k<<<M, blk, 0, stream>>>(hbuf, wln2, xn, C);

    cast_w<<<(I * C) / 2048, blk, 0, stream>>>(wg, arena, I * C);
    gemm8<0, 8><<<dim3((I / 256) * (M / 256)), blk8, 0, stream>>>(xn, arena, nullptr, nullptr, gbuf, M, I, C, 1.f);
    cast_w<<<(I * C) / 2048, blk, 0, stream>>>(wu, arena, I * C);
    gemm8<3, 8><<<dim3((I / 256) * (M / 256)), blk8, 0, stream>>>(xn, arena, nullptr, gbuf, gbuf, M, I, C, 1.f);
    cast_w<<<(C * I) / 2048, blk, 0, stream>>>(wd, arena, C * I);
    gemm8<2, 4><<<dim3((C / 256) * (M / 128)), blk8, 0, stream>>>(gbuf, arena, hbuf, nullptr, out, M, C, I, 1.f);
}

// Round 13
// 721.761 us; speedup vs baseline: 1.2224x; 1.0012x over previous
//
#include <hip/hip_runtime.h>
#include <stdint.h>

typedef unsigned short u16;
typedef unsigned int   u32;
typedef short s16x8 __attribute__((ext_vector_type(8)));
typedef u16   u16x8 __attribute__((ext_vector_type(8)));
typedef u32   u32x4 __attribute__((ext_vector_type(4)));
typedef float f32x4 __attribute__((ext_vector_type(4)));

__device__ __forceinline__ u16 f2bf(float f) {
    u32 u = __float_as_uint(f);
    u32 r = u + 0x7fffu + ((u >> 16) & 1u);   // RNE
    return (u16)(r >> 16);
}
__device__ __forceinline__ float bf2f(u16 h) {
    return __uint_as_float(((u32)h) << 16);
}

// pack 2 f32 -> 2 bf16 (RNE), low word = a
__device__ __forceinline__ u32 cvtpk(float a, float b) {
    u32 r;
    asm("v_cvt_pk_bf16_f32 %0, %1, %2" : "=v"(r) : "v"(a), "v"(b));
    return r;
}
// swap a.lanes[32:63] <-> b.lanes[0:31]
__device__ __forceinline__ void swap32(u32& a, u32& b) {
#if __has_builtin(__builtin_amdgcn_permlane32_swap)
    auto r = __builtin_amdgcn_permlane32_swap(a, b, false, false);
    a = r[0]; b = r[1];
#else
    asm volatile("v_permlane32_swap_b32 %0, %1" : "+v"(a), "+v"(b));
#endif
}
// swap a's odd 16-rows <-> b's even 16-rows
__device__ __forceinline__ void swap16(u32& a, u32& b) {
#if __has_builtin(__builtin_amdgcn_permlane16_swap)
    auto r = __builtin_amdgcn_permlane16_swap(a, b, false, false);
    a = r[0]; b = r[1];
#else
    asm volatile("v_permlane16_swap_b32 %0, %1" : "+v"(a), "+v"(b));
#endif
}

// async global->LDS, 16B per lane. LDS dest = wave-uniform base + lane*16.
#define GLD16(gp, lp) __builtin_amdgcn_global_load_lds(                          \
    (const __attribute__((address_space(1))) void*)(uintptr_t)(gp),             \
    (__attribute__((address_space(3))) void*)(u32)(uintptr_t)(lp), 16, 0, 0)

#define FENCE asm volatile("" ::: "memory")

template<int N> __device__ __forceinline__ void waitv() {
    if constexpr (N == 0)      asm volatile("s_waitcnt vmcnt(0)" ::: "memory");
    else if constexpr (N == 2) asm volatile("s_waitcnt vmcnt(2)" ::: "memory");
    else if constexpr (N == 3) asm volatile("s_waitcnt vmcnt(3)" ::: "memory");
    else                       asm volatile("s_waitcnt vmcnt(4)" ::: "memory");
}

// ---------------------------------------------------------------------------
// fp32 -> bf16 weight cast, 8 elems/thread
// ---------------------------------------------------------------------------
__global__ __launch_bounds__(256)
void cast_w(const float* __restrict__ in, u16* __restrict__ out, int n)
{
    const int i = (blockIdx.x * 256 + threadIdx.x) * 8;
    if (i >= n) return;
    f32x4 a = *(const f32x4*)(in + i);
    f32x4 b = *(const f32x4*)(in + i + 4);
    u16x8 o;
    o[0] = f2bf(a[0]); o[1] = f2bf(a[1]); o[2] = f2bf(a[2]); o[3] = f2bf(a[3]);
    o[4] = f2bf(b[0]); o[5] = f2bf(b[1]); o[6] = f2bf(b[2]); o[7] = f2bf(b[3]);
    *(u16x8*)(out + i) = o;
}

// ---------------------------------------------------------------------------
// RMSNorm: one block per row (C=2048), fp32 in -> bf16 out
// ---------------------------------------------------------------------------
__global__ __launch_bounds__(256)
void rmsnorm_k(const float* __restrict__ x, const float* __restrict__ wln,
               u16* __restrict__ out, int C)
{
    const int row = blockIdx.x;
    const int tid = threadIdx.x;
    const float* xr = x + (size_t)row * C;
    f32x4 a = *(const f32x4*)(xr + tid * 8);
    f32x4 b = *(const f32x4*)(xr + tid * 8 + 4);
    float s = a[0]*a[0] + a[1]*a[1] + a[2]*a[2] + a[3]*a[3]
            + b[0]*b[0] + b[1]*b[1] + b[2]*b[2] + b[3]*b[3];
    #pragma unroll
    for (int off = 1; off < 64; off <<= 1) s += __shfl_xor(s, off);
    __shared__ float red[4];
    if ((tid & 63) == 0) red[tid >> 6] = s;
    __syncthreads();
    float tot = red[0] + red[1] + red[2] + red[3];
    float inv = rsqrtf(tot / (float)C + 1e-6f);
    f32x4 wa = *(const f32x4*)(wln + tid * 8);
    f32x4 wb = *(const f32x4*)(wln + tid * 8 + 4);
    u16x8 o;
    o[0] = f2bf(a[0]*inv*wa[0]); o[1] = f2bf(a[1]*inv*wa[1]);
    o[2] = f2bf(a[2]*inv*wa[2]); o[3] = f2bf(a[3]*inv*wa[3]);
    o[4] = f2bf(b[0]*inv*wb[0]); o[5] = f2bf(b[1]*inv*wb[1]);
    o[6] = f2bf(b[2]*inv*wb[2]); o[7] = f2bf(b[3]*inv*wb[3]);
    *(u16x8*)(out + (size_t)row * C + tid * 8) = o;
}

// ---------------------------------------------------------------------------
// Pipelined 8-phase GEMM (R10, measured 145us MLP / 948TF): C = A @ W^T.
// Tile BM x 256, BK=64, 8 waves, Gray-code quadrant walk. Each phase:
//   {barrier; lgkm(0); MFMA (frags read LAST phase); ds_read next frags;
//    stage slot; [vmcnt(2) at P4/P8]}
// MODE 0: bf16  1: bf16*scale  2: fp32 resid+acc  3: bf16 silu(aux)*acc
// MODE 5: QK split -- col<2048 -> Cout bf16*scale, else aux (bf16), N=4096
// ---------------------------------------------------------------------------
template<int MODE, int MR>
__global__ __launch_bounds__(512, 1)
void gemm8(const u16* __restrict__ A, const u16* __restrict__ W,
           const float* __restrict__ resid, const u16* __restrict__ aux,
           void* __restrict__ Cout, int M, int N, int K, float scale)
{
    constexpr int BM  = MR * 32;
    constexpr int MR2 = MR / 2;
    constexpr int SRA = MR * 8;
    constexpr int AL  = BM / 128;
    __shared__ __align__(16) u16 lds[2][(BM + 256) * 64];

    const int tid  = threadIdx.x;
    const int lane = tid & 63;
    const int w    = tid >> 6;
    const int wm   = w >> 2;
    const int wn   = w & 3;

    const int gx  = N >> 8;
    const int nwg = gridDim.x;
    const int sid = ((int)blockIdx.x & 7) * (nwg >> 3) + ((int)blockIdx.x >> 3);
    const int brow = (sid / gx) * BM;
    const int bcol = (sid % gx) * 256;

    const int KT = K >> 6;
    const int NI = KT >> 1;

    f32x4 acc[MR][4] = {};

    auto stageA = [&](int buf, int g, int kt) {
        #pragma unroll
        for (int j = 0; j < AL; ++j) {
            const int p   = j * 64 + (tid >> 3);
            const int row = ((p & ~(SRA - 1)) << 1) | (g * SRA) | (p & (SRA - 1));
            const int ch  = (tid & 7) ^ (row & 7);
            const u16* src = A + (size_t)(brow + row) * K + kt * 64 + ch * 8;
            const int p0  = j * 64 + (w << 3);
            const int r0  = ((p0 & ~(SRA - 1)) << 1) | (g * SRA) | (p0 & (SRA - 1));
            GLD16(src, &lds[buf][0] + r0 * 64);
        }
    };
    auto stageB = [&](int buf, int g, int kt) {
        #pragma unroll
        for (int j = 0; j < 2; ++j) {
            const int p   = j * 64 + (tid >> 3);
            const int row = ((p & ~31) << 1) | (g * 32) | (p & 31);
            const int ch  = (tid & 7) ^ (row & 7);
            const u16* src = W + (size_t)(bcol + row) * K + kt * 64 + ch * 8;
            const int p0  = j * 64 + (w << 3);
            const int r0  = ((p0 & ~31) << 1) | (g * 32) | (p0 & 31);
            GLD16(src, &lds[buf][BM * 64] + r0 * 64);
        }
    };

#define LDAF(AF, MH, BUF)                                                        \
    _Pragma("unroll") for (int f = 0; f < MR2; ++f)                              \
    _Pragma("unroll") for (int ks = 0; ks < 2; ++ks) {                           \
        const int row = wm * (BM / 2) + (MH) * (BM / 4) + f * 16 + (lane & 15);  \
        const int ch  = (ks * 4 + (lane >> 4)) ^ (row & 7);                      \
        AF[f][ks] = *(const s16x8*)(&lds[BUF][0] + row * 64 + ch * 8);           \
    }
#define LDBF(BQ, NH, BUF)                                                        \
    _Pragma("unroll") for (int g = 0; g < 2; ++g)                                \
    _Pragma("unroll") for (int ks = 0; ks < 2; ++ks) {                           \
        const int row = wn * 64 + (NH) * 32 + g * 16 + (lane & 15);              \
        const int ch  = (ks * 4 + (lane >> 4)) ^ (row & 7);                      \
        BQ[g][ks] = *(const s16x8*)(&lds[BUF][BM * 64] + row * 64 + ch * 8);     \
    }
#define MFQ(AF, BQ, MH, NH)                                                      \
    __builtin_amdgcn_s_setprio(1);                                               \
    _Pragma("unroll") for (int f = 0; f < MR2; ++f)                              \
    _Pragma("unroll") for (int g = 0; g < 2; ++g)                                \
    _Pragma("unroll") for (int ks = 0; ks < 2; ++ks)                             \
        acc[(MH) * MR2 + f][(NH) * 2 + g] =                                      \
            __builtin_amdgcn_mfma_f32_16x16x32_bf16(                             \
                AF[f][ks], BQ[g][ks], acc[(MH) * MR2 + f][(NH) * 2 + g], 0, 0, 0); \
    __builtin_amdgcn_s_setprio(0);
#define PH_ENTRY FENCE; __builtin_amdgcn_s_barrier();                            \
    asm volatile("s_waitcnt lgkmcnt(0)" ::: "memory"); FENCE

    s16x8 af[MR2][2], bqA[2][2], bqB[2][2];

    // prologue: t0 full -> buf0; t1's B0,A0,B1 -> buf1 (A1 staged at P1).
    stageB(0, 0, 0); stageA(0, 0, 0); stageB(0, 1, 0); stageA(0, 1, 0);
    stageB(1, 0, 1); stageA(1, 0, 1); stageB(1, 1, 1);
    waitv<0>();
    FENCE; __builtin_amdgcn_s_barrier(); FENCE;
    LDAF(af, 0, 0) LDBF(bqA, 0, 0)

    for (int it = 0; it < NI; ++it) {
        const int t1  = 2 * it + 1;
        const int t0n = 2 * it + 2;
        const int t1n = 2 * it + 3;
        const bool last = (it == NI - 1);

        // P1: Q(0,0) buf0
        PH_ENTRY; MFQ(af, bqA, 0, 0)
        LDBF(bqB, 1, 0)
        stageA(1, 1, t1);
        // P2: Q(0,1) buf0
        PH_ENTRY; MFQ(af, bqB, 0, 1)
        LDAF(af, 1, 0)
        if (!last) stageB(0, 0, t0n);
        // P3: Q(1,1) buf0
        PH_ENTRY; MFQ(af, bqB, 1, 1)
        if (!last) stageA(0, 0, t0n);
        // P4: Q(1,0) buf0 -> buffer switch pre-read
        PH_ENTRY; MFQ(af, bqA, 1, 0)
        if (!last) stageB(0, 1, t0n);
        if (last) { waitv<0>(); } else { waitv<2>(); }
        LDAF(af, 0, 1) LDBF(bqA, 0, 1)
        // P5: Q(0,0) buf1
        PH_ENTRY; MFQ(af, bqA, 0, 0)
        LDBF(bqB, 1, 1)
        if (!last) stageA(0, 1, t0n);
        // P6: Q(0,1) buf1
        PH_ENTRY; MFQ(af, bqB, 0, 1)
        LDAF(af, 1, 1)
        if (!last) stageB(1, 0, t1n);
        // P7: Q(1,1) buf1
        PH_ENTRY; MFQ(af, bqB, 1, 1)
        if (!last) stageA(1, 0, t1n);
        // P8: Q(1,0) buf1 -> buffer switch pre-read (skip on last)
        PH_ENTRY; MFQ(af, bqA, 1, 0)
        if (!last) {
            stageB(1, 1, t1n);
            waitv<2>();
            LDAF(af, 0, 0) LDBF(bqA, 0, 0)
        }
    }
#undef LDAF
#undef LDBF
#undef MFQ
#undef PH_ENTRY

    // epilogue: D layout col=lane&15, row=(lane>>4)*4+r
    const int er = (lane >> 4) * 4;
    const int ec = lane & 15;
    #pragma unroll
    for (int i = 0; i < MR; ++i) {
        #pragma unroll
        for (int j = 0; j < 4; ++j) {
            #pragma unroll
            for (int r = 0; r < 4; ++r) {
                const int row = brow + wm * (BM / 2) + i * 16 + er + r;
                const int col = bcol + wn * 64 + j * 16 + ec;
                const float va = acc[i][j][r];
                if (MODE == 5) {
                    if (col < 2048)
                        ((u16*)Cout)[(size_t)row * 2048 + col] = f2bf(va * scale);
                    else
                        ((u16*)aux)[(size_t)row * 2048 + (col - 2048)] = f2bf(va);
                } else {
                    const size_t idx = (size_t)row * N + col;
                    if (MODE == 0)      ((u16*)Cout)[idx] = f2bf(va);
                    else if (MODE == 1) ((u16*)Cout)[idx] = f2bf(va * scale);
                    else if (MODE == 2) ((float*)Cout)[idx] = resid[idx] + va;
                    else {
                        const float g  = bf2f(aux[idx]);
                        const float sg = g / (1.0f + exp2f(-g * 1.4426950408889634f));
                        ((u16*)Cout)[idx] = f2bf(sg * va);
                    }
                }
            }
        }
    }
}

// ---------------------------------------------------------------------------
// Flash attention fwd (R9/R10 structure): 4 waves x 32 q-rows = 128
// q-rows/block, 512 blocks = 2 blocks/CU; T12 swapped-QK^T in-register
// softmax, T13 defer-max, T14 async-stage, XOR-swizzled K/V dbuf.
// q,k,o: [b][t][h*128+d] bf16.  v PRE-TRANSPOSED: [h*128+d][b*2048+t].
// ---------------------------------------------------------------------------
__global__ __launch_bounds__(256, 2)
void flash_attn(const u16* __restrict__ q, const u16* __restrict__ k,
                const u16* __restrict__ vT, u16* __restrict__ o)
{
    __shared__ __align__(16) u16 Kt[2][64 * 128];
    __shared__ __align__(16) u16 Vt[2][128 * 64];
    const int tid  = threadIdx.x;
    const int lane = tid & 63;
    const int w    = tid >> 6;
    const int qtile = blockIdx.x;
    const int bh    = blockIdx.y;
    const int b = bh >> 4, h = bh & 15;
    const size_t head  = ((size_t)b * 2048) * 2048 + (size_t)h * 128;
    const size_t vbase = ((size_t)h * 128) * 4096 + (size_t)b * 2048;

    s16x8 qf[2][4];
    #pragma unroll
    for (int qi = 0; qi < 2; ++qi) {
        const int tq = qtile * 128 + w * 32 + qi * 16 + (lane & 15);
        const u16* qp = q + head + (size_t)tq * 2048 + (lane >> 4) * 8;
        #pragma unroll
        for (int dk = 0; dk < 4; ++dk) qf[qi][dk] = *(const s16x8*)(qp + dk * 32);
    }

    f32x4 oa[2][8] = {};
    float m_r[2] = {-1e30f, -1e30f};
    float l_r[2] = {0.f, 0.f};

    const int krow = tid >> 2;
    const int kc0  = (tid & 3) * 32;
    const int vd   = tid >> 1;
    const int vk0  = (tid & 1) * 32;
    const u16* kg = k + head + (size_t)krow * 2048 + kc0;
    const u16* vg = vT + vbase + (size_t)vd * 4096 + vk0;
    u32 kwo[4], vwo[4];
    #pragma unroll
    for (int c = 0; c < 4; ++c) {
        kwo[c] = (u32)((krow * 256 + (kc0 + c * 8) * 2) ^ ((krow & 7) << 4));
        vwo[c] = (u32)((vd * 128 + (vk0 + c * 8) * 2)   ^ ((vd & 7) << 4));
    }

    s16x8 kr[4], vr[4];
    #pragma unroll
    for (int c = 0; c < 4; ++c) {
        kr[c] = *(const s16x8*)(kg + c * 8);
        vr[c] = *(const s16x8*)(vg + c * 8);
    }

    for (int kb = 0; kb < 32; ++kb) {
        const int cur = kb & 1;
        char* KtB = (char*)&Kt[cur][0];
        char* VtB = (char*)&Vt[cur][0];
        #pragma unroll
        for (int c = 0; c < 4; ++c) {
            *(s16x8*)(KtB + kwo[c]) = kr[c];
            *(s16x8*)(VtB + vwo[c]) = vr[c];
        }
        if (kb + 1 < 32) {
            const int k0n = (kb + 1) * 64;
            #pragma unroll
            for (int c = 0; c < 4; ++c) {
                kr[c] = *(const s16x8*)(kg + (size_t)k0n * 2048 + c * 8);
                vr[c] = *(const s16x8*)(vg + k0n + c * 8);
            }
        }
        asm volatile("s_waitcnt lgkmcnt(0)" ::: "memory");
        __builtin_amdgcn_s_barrier();
        FENCE;

        f32x4 st[2][4] = {};
        __builtin_amdgcn_s_setprio(1);
        #pragma unroll
        for (int kt = 0; kt < 4; ++kt) {
            const int row = kt * 16 + (lane & 15);
            s16x8 kf[4];
            #pragma unroll
            for (int dk = 0; dk < 4; ++dk) {
                const int dcol = dk * 32 + (lane >> 4) * 8;
                kf[dk] = *(const s16x8*)(KtB + ((row * 256 + dcol * 2) ^ ((row & 7) << 4)));
            }
            #pragma unroll
            for (int qi = 0; qi < 2; ++qi)
                #pragma unroll
                for (int dk = 0; dk < 4; ++dk)
                    st[qi][kt] = __builtin_amdgcn_mfma_f32_16x16x32_bf16(kf[dk], qf[qi][dk], st[qi][kt], 0, 0, 0);
        }
        __builtin_amdgcn_s_setprio(0);

        float mx[2];
        #pragma unroll
        for (int qi = 0; qi < 2; ++qi) {
            float m0 = fmaxf(fmaxf(st[qi][0][0], st[qi][0][1]), fmaxf(st[qi][0][2], st[qi][0][3]));
            float m1 = fmaxf(fmaxf(st[qi][1][0], st[qi][1][1]), fmaxf(st[qi][1][2], st[qi][1][3]));
            float m2 = fmaxf(fmaxf(st[qi][2][0], st[qi][2][1]), fmaxf(st[qi][2][2], st[qi][2][3]));
            float m3 = fmaxf(fmaxf(st[qi][3][0], st[qi][3][1]), fmaxf(st[qi][3][2], st[qi][3][3]));
            float m0123 = fmaxf(fmaxf(m0, m1), fmaxf(m2, m3));
            m0123 = fmaxf(m0123, __shfl_xor(m0123, 16));
            m0123 = fmaxf(m0123, __shfl_xor(m0123, 32));
            mx[qi] = m0123;
        }
        const bool grow = (mx[0] > m_r[0] + 8.f) || (mx[1] > m_r[1] + 8.f);
        if (__any(grow)) {
            #pragma unroll
            for (int qi = 0; qi < 2; ++qi) {
                const float mn = fmaxf(m_r[qi], mx[qi]);
                const float sc = exp2f(m_r[qi] - mn);
                m_r[qi] = mn;
                l_r[qi] *= sc;
                const float s0 = __shfl(sc, (lane >> 4) * 4 + 0);
                const float s1 = __shfl(sc, (lane >> 4) * 4 + 1);
                const float s2 = __shfl(sc, (lane >> 4) * 4 + 2);
                const float s3 = __shfl(sc, (lane >> 4) * 4 + 3);
                #pragma unroll
                for (int ni = 0; ni < 8; ++ni) {
                    oa[qi][ni][0] *= s0; oa[qi][ni][1] *= s1;
                    oa[qi][ni][2] *= s2; oa[qi][ni][3] *= s3;
                }
            }
        }

        s16x8 pa[2][2];
        #pragma unroll
        for (int qi = 0; qi < 2; ++qi) {
            float sum = 0.f;
            #pragma unroll
            for (int kt = 0; kt < 4; ++kt)
                #pragma unroll
                for (int r = 0; r < 4; ++r) {
                    const float p = exp2f(st[qi][kt][r] - m_r[qi]);
                    st[qi][kt][r] = p;
                    sum += p;
                }
            sum += __shfl_xor(sum, 16);
            sum += __shfl_xor(sum, 32);
            l_r[qi] += sum;

            u32 q01[4], q23[4];
            #pragma unroll
            for (int kt = 0; kt < 4; ++kt) {
                q01[kt] = cvtpk(st[qi][kt][0], st[qi][kt][1]);
                q23[kt] = cvtpk(st[qi][kt][2], st[qi][kt][3]);
            }
            #pragma unroll
            for (int ks = 0; ks < 2; ++ks) {
                u32 X = q01[2 * ks], Y = q01[2 * ks + 1];
                swap32(X, Y); swap16(X, Y);
                u32 U = q23[2 * ks], V = q23[2 * ks + 1];
                swap32(U, V); swap16(U, V);
                u32x4 t; t[0] = X; t[1] = U; t[2] = Y; t[3] = V;
                pa[qi][ks] = __builtin_bit_cast(s16x8, t);
            }
        }

        __builtin_amdgcn_s_setprio(1);
        #pragma unroll
        for (int ks = 0; ks < 2; ++ks) {
            const int keyb = ks * 32 + (lane >> 4) * 8;
            #pragma unroll
            for (int ni = 0; ni < 8; ++ni) {
                const int dd = ni * 16 + (lane & 15);
                s16x8 vf = *(const s16x8*)(VtB + ((dd * 128 + keyb * 2) ^ ((dd & 7) << 4)));
                #pragma unroll
                for (int qi = 0; qi < 2; ++qi)
                    oa[qi][ni] = __builtin_amdgcn_mfma_f32_16x16x32_bf16(pa[qi][ks], vf, oa[qi][ni], 0, 0, 0);
            }
        }
        __builtin_amdgcn_s_setprio(0);
    }
    #pragma unroll
    for (int qi = 0; qi < 2; ++qi) {
        #pragma unroll
        for (int r = 0; r < 4; ++r) {
            const float inv = 1.0f / __shfl(l_r[qi], (lane >> 4) * 4 + r);
            const int tout = qtile * 128 + w * 32 + qi * 16 + (lane >> 4) * 4 + r;
            u16* op = o + head + (size_t)tout * 2048 + (lane & 15);
            #pragma unroll
            for (int ni = 0; ni < 8; ++ni)
                op[ni * 16] = f2bf(oa[qi][ni][r] * inv);
        }
    }
}

// ---------------------------------------------------------------------------
extern "C" void kernel_launch(void* const* d_in, const int* in_sizes, int n_in,
                              void* d_out, int out_size, void* d_ws, size_t ws_size,
                              hipStream_t stream)
{
    (void)in_sizes; (void)n_in; (void)out_size; (void)ws_size;
    const float* x    = (const float*)d_in[0];
    const float* wln1 = (const float*)d_in[1];
    const float* wq   = (const float*)d_in[2];
    const float* wk   = (const float*)d_in[3];
    const float* wv   = (const float*)d_in[4];
    const float* wo   = (const float*)d_in[5];
    const float* wln2 = (const float*)d_in[6];
    const float* wg   = (const float*)d_in[7];
    const float* wu   = (const float*)d_in[8];
    const float* wd   = (const float*)d_in[9];
    float* out = (float*)d_out;

    const size_t MB = 1024ull * 1024ull;
    char* ws = (char*)d_ws;
    u16*   arena = (u16*)(ws + 0);          // 32 MB: bf16 weight arena (reused)
    float* hbuf  = (float*)(ws + 32 * MB);  // 32 MB: x + attn residual (fp32)
    u16*   xn    = (u16*)(ws + 64 * MB);    // 16 MB: rmsnorm output (bf16)
    u16*   qb    = (u16*)(ws + 80 * MB);    // 16 MB
    u16*   kbuf  = (u16*)(ws + 96 * MB);    // 16 MB
    u16*   vT    = (u16*)(ws + 112 * MB);   // 16 MB: V transposed [h*128+d][b*2048+t]
    u16*   abuf  = (u16*)(ws + 128 * MB);   // 16 MB (ends 144 MB)
    u16*   gbuf  = (u16*)(ws + 80 * MB);    // 64 MB, aliases q..attn (dead then)

    const int M = 4096, C = 2048, I = 8192;
    const float qscale = 0.1275164899f;     // (1/sqrt(128)) * log2(e)
    dim3 blk(256);
    dim3 blk8(512);

    rmsnorm_k<<<M, blk, 0, stream>>>(x, wln1, xn, C);

    // fused Q+K: arena = [wq ; wk] (4096 x 2048), one gemm8 with split epilogue
    cast_w<<<(C * C) / 2048, blk, 0, stream>>>(wq, arena, C * C);
    cast_w<<<(C * C) / 2048, blk, 0, stream>>>(wk, arena + (size_t)C * C, C * C);
    gemm8<5, 4><<<dim3((2 * C / 256) * (M / 128)), blk8, 0, stream>>>(
        xn, arena, nullptr, kbuf, qb, M, 2 * C, C, qscale);

    cast_w<<<(C * C) / 2048, blk, 0, stream>>>(wv, arena, C * C);
    // V^T = Wv @ Xn^T : operand-swapped GEMM -> coalesced transposed output
    gemm8<0, 4><<<dim3((M / 256) * (C / 128)), blk8, 0, stream>>>(arena, xn, nullptr, nullptr, vT, C, M, C, 1.f);

    flash_attn<<<dim3(2048 / 128, 32), blk, 0, stream>>>(qb, kbuf, vT, abuf);

    cast_w<<<(C * C) / 2048, blk, 0, stream>>>(wo, arena, C * C);
    gemm8<2, 4><<<dim3((C / 256) * (M / 128)), blk8, 0, stream>>>(abuf, arena, x, nullptr, hbuf, M, C, C, 1.f);

    rmsnorm_k<<<M, blk, 0, stream>>>(hbuf, wln2, xn, C);

    cast_w<<<(I * C) / 2048, blk, 0, stream>>>(wg, arena, I * C);
    gemm8<0, 8><<<dim3((I / 256) * (M / 256)), blk8, 0, stream>>>(xn, arena, nullptr, nullptr, gbuf, M, I, C, 1.f);
    cast_w<<<(I * C) / 2048, blk, 0, stream>>>(wu, arena, I * C);
    gemm8<3, 8><<<dim3((I / 256) * (M / 256)), blk8, 0, stream>>>(xn, arena, nullptr, gbuf, gbuf, M, I, C, 1.f);
    cast_w<<<(C * I) / 2048, blk, 0, stream>>>(wd, arena, C * I);
    gemm8<2, 4><<<dim3((C / 256) * (M / 128)), blk8, 0, stream>>>(gbuf, arena, hbuf, nullptr, out, M, C, I, 1.f);
}

// Round 14
// 718.961 us; speedup vs baseline: 1.2272x; 1.0039x over previous
//
#include <hip/hip_runtime.h>
#include <stdint.h>

typedef unsigned short u16;
typedef unsigned int   u32;
typedef short s16x8 __attribute__((ext_vector_type(8)));
typedef u16   u16x8 __attribute__((ext_vector_type(8)));
typedef u32   u32x4 __attribute__((ext_vector_type(4)));
typedef float f32x4 __attribute__((ext_vector_type(4)));

__device__ __forceinline__ u16 f2bf(float f) {
    u32 u = __float_as_uint(f);
    u32 r = u + 0x7fffu + ((u >> 16) & 1u);   // RNE
    return (u16)(r >> 16);
}
__device__ __forceinline__ float bf2f(u16 h) {
    return __uint_as_float(((u32)h) << 16);
}

// pack 2 f32 -> 2 bf16 (RNE), low word = a
__device__ __forceinline__ u32 cvtpk(float a, float b) {
    u32 r;
    asm("v_cvt_pk_bf16_f32 %0, %1, %2" : "=v"(r) : "v"(a), "v"(b));
    return r;
}
// swap a.lanes[32:63] <-> b.lanes[0:31]
__device__ __forceinline__ void swap32(u32& a, u32& b) {
#if __has_builtin(__builtin_amdgcn_permlane32_swap)
    auto r = __builtin_amdgcn_permlane32_swap(a, b, false, false);
    a = r[0]; b = r[1];
#else
    asm volatile("v_permlane32_swap_b32 %0, %1" : "+v"(a), "+v"(b));
#endif
}
// swap a's odd 16-rows <-> b's even 16-rows
__device__ __forceinline__ void swap16(u32& a, u32& b) {
#if __has_builtin(__builtin_amdgcn_permlane16_swap)
    auto r = __builtin_amdgcn_permlane16_swap(a, b, false, false);
    a = r[0]; b = r[1];
#else
    asm volatile("v_permlane16_swap_b32 %0, %1" : "+v"(a), "+v"(b));
#endif
}

// async global->LDS, 16B per lane. LDS dest = wave-uniform base + lane*16.
#define GLD16(gp, lp) __builtin_amdgcn_global_load_lds(                          \
    (const __attribute__((address_space(1))) void*)(uintptr_t)(gp),             \
    (__attribute__((address_space(3))) void*)(u32)(uintptr_t)(lp), 16, 0, 0)

#define FENCE asm volatile("" ::: "memory")

template<int N> __device__ __forceinline__ void waitv() {
    if constexpr (N == 0)      asm volatile("s_waitcnt vmcnt(0)" ::: "memory");
    else if constexpr (N == 2) asm volatile("s_waitcnt vmcnt(2)" ::: "memory");
    else if constexpr (N == 3) asm volatile("s_waitcnt vmcnt(3)" ::: "memory");
    else                       asm volatile("s_waitcnt vmcnt(4)" ::: "memory");
}

// ---------------------------------------------------------------------------
// fp32 -> bf16 weight cast, 8 elems/thread
// ---------------------------------------------------------------------------
__global__ __launch_bounds__(256)
void cast_w(const float* __restrict__ in, u16* __restrict__ out, int n)
{
    const int i = (blockIdx.x * 256 + threadIdx.x) * 8;
    if (i >= n) return;
    f32x4 a = *(const f32x4*)(in + i);
    f32x4 b = *(const f32x4*)(in + i + 4);
    u16x8 o;
    o[0] = f2bf(a[0]); o[1] = f2bf(a[1]); o[2] = f2bf(a[2]); o[3] = f2bf(a[3]);
    o[4] = f2bf(b[0]); o[5] = f2bf(b[1]); o[6] = f2bf(b[2]); o[7] = f2bf(b[3]);
    *(u16x8*)(out + i) = o;
}

// ---------------------------------------------------------------------------
// RMSNorm: one block per row (C=2048), fp32 in -> bf16 out
// ---------------------------------------------------------------------------
__global__ __launch_bounds__(256)
void rmsnorm_k(const float* __restrict__ x, const float* __restrict__ wln,
               u16* __restrict__ out, int C)
{
    const int row = blockIdx.x;
    const int tid = threadIdx.x;
    const float* xr = x + (size_t)row * C;
    f32x4 a = *(const f32x4*)(xr + tid * 8);
    f32x4 b = *(const f32x4*)(xr + tid * 8 + 4);
    float s = a[0]*a[0] + a[1]*a[1] + a[2]*a[2] + a[3]*a[3]
            + b[0]*b[0] + b[1]*b[1] + b[2]*b[2] + b[3]*b[3];
    #pragma unroll
    for (int off = 1; off < 64; off <<= 1) s += __shfl_xor(s, off);
    __shared__ float red[4];
    if ((tid & 63) == 0) red[tid >> 6] = s;
    __syncthreads();
    float tot = red[0] + red[1] + red[2] + red[3];
    float inv = rsqrtf(tot / (float)C + 1e-6f);
    f32x4 wa = *(const f32x4*)(wln + tid * 8);
    f32x4 wb = *(const f32x4*)(wln + tid * 8 + 4);
    u16x8 o;
    o[0] = f2bf(a[0]*inv*wa[0]); o[1] = f2bf(a[1]*inv*wa[1]);
    o[2] = f2bf(a[2]*inv*wa[2]); o[3] = f2bf(a[3]*inv*wa[3]);
    o[4] = f2bf(b[0]*inv*wb[0]); o[5] = f2bf(b[1]*inv*wb[1]);
    o[6] = f2bf(b[2]*inv*wb[2]); o[7] = f2bf(b[3]*inv*wb[3]);
    *(u16x8*)(out + (size_t)row * C + tid * 8) = o;
}

// ---------------------------------------------------------------------------
// Pipelined 8-phase GEMM (R10, measured 145us MLP / 948TF): C = A @ W^T.
// Tile BM x 256, BK=64, 8 waves, Gray-code quadrant walk. Each phase:
//   {barrier; lgkm(0); MFMA (frags read LAST phase); ds_read next frags;
//    stage slot; [vmcnt(2) at P4/P8]}
// MODE 0: bf16  1: bf16*scale  2: fp32 resid+acc  3: bf16 silu(aux)*acc
// MODE 5: QK split -- col<2048 -> Cout bf16*scale, else aux (bf16), N=4096
// ---------------------------------------------------------------------------
template<int MODE, int MR>
__global__ __launch_bounds__(512, 1)
void gemm8(const u16* __restrict__ A, const u16* __restrict__ W,
           const float* __restrict__ resid, const u16* __restrict__ aux,
           void* __restrict__ Cout, int M, int N, int K, float scale)
{
    constexpr int BM  = MR * 32;
    constexpr int MR2 = MR / 2;
    constexpr int SRA = MR * 8;
    constexpr int AL  = BM / 128;
    __shared__ __align__(16) u16 lds[2][(BM + 256) * 64];

    const int tid  = threadIdx.x;
    const int lane = tid & 63;
    const int w    = tid >> 6;
    const int wm   = w >> 2;
    const int wn   = w & 3;

    const int gx  = N >> 8;
    const int nwg = gridDim.x;
    const int sid = ((int)blockIdx.x & 7) * (nwg >> 3) + ((int)blockIdx.x >> 3);
    const int brow = (sid / gx) * BM;
    const int bcol = (sid % gx) * 256;

    const int KT = K >> 6;
    const int NI = KT >> 1;

    f32x4 acc[MR][4] = {};

    auto stageA = [&](int buf, int g, int kt) {
        #pragma unroll
        for (int j = 0; j < AL; ++j) {
            const int p   = j * 64 + (tid >> 3);
            const int row = ((p & ~(SRA - 1)) << 1) | (g * SRA) | (p & (SRA - 1));
            const int ch  = (tid & 7) ^ (row & 7);
            const u16* src = A + (size_t)(brow + row) * K + kt * 64 + ch * 8;
            const int p0  = j * 64 + (w << 3);
            const int r0  = ((p0 & ~(SRA - 1)) << 1) | (g * SRA) | (p0 & (SRA - 1));
            GLD16(src, &lds[buf][0] + r0 * 64);
        }
    };
    auto stageB = [&](int buf, int g, int kt) {
        #pragma unroll
        for (int j = 0; j < 2; ++j) {
            const int p   = j * 64 + (tid >> 3);
            const int row = ((p & ~31) << 1) | (g * 32) | (p & 31);
            const int ch  = (tid & 7) ^ (row & 7);
            const u16* src = W + (size_t)(bcol + row) * K + kt * 64 + ch * 8;
            const int p0  = j * 64 + (w << 3);
            const int r0  = ((p0 & ~31) << 1) | (g * 32) | (p0 & 31);
            GLD16(src, &lds[buf][BM * 64] + r0 * 64);
        }
    };

#define LDAF(AF, MH, BUF)                                                        \
    _Pragma("unroll") for (int f = 0; f < MR2; ++f)                              \
    _Pragma("unroll") for (int ks = 0; ks < 2; ++ks) {                           \
        const int row = wm * (BM / 2) + (MH) * (BM / 4) + f * 16 + (lane & 15);  \
        const int ch  = (ks * 4 + (lane >> 4)) ^ (row & 7);                      \
        AF[f][ks] = *(const s16x8*)(&lds[BUF][0] + row * 64 + ch * 8);           \
    }
#define LDBF(BQ, NH, BUF)                                                        \
    _Pragma("unroll") for (int g = 0; g < 2; ++g)                                \
    _Pragma("unroll") for (int ks = 0; ks < 2; ++ks) {                           \
        const int row = wn * 64 + (NH) * 32 + g * 16 + (lane & 15);              \
        const int ch  = (ks * 4 + (lane >> 4)) ^ (row & 7);                      \
        BQ[g][ks] = *(const s16x8*)(&lds[BUF][BM * 64] + row * 64 + ch * 8);     \
    }
#define MFQ(AF, BQ, MH, NH)                                                      \
    __builtin_amdgcn_s_setprio(1);                                               \
    _Pragma("unroll") for (int f = 0; f < MR2; ++f)                              \
    _Pragma("unroll") for (int g = 0; g < 2; ++g)                                \
    _Pragma("unroll") for (int ks = 0; ks < 2; ++ks)                             \
        acc[(MH) * MR2 + f][(NH) * 2 + g] =                                      \
            __builtin_amdgcn_mfma_f32_16x16x32_bf16(                             \
                AF[f][ks], BQ[g][ks], acc[(MH) * MR2 + f][(NH) * 2 + g], 0, 0, 0); \
    __builtin_amdgcn_s_setprio(0);
#define PH_ENTRY FENCE; __builtin_amdgcn_s_barrier();                            \
    asm volatile("s_waitcnt lgkmcnt(0)" ::: "memory"); FENCE

    s16x8 af[MR2][2], bqA[2][2], bqB[2][2];

    // prologue: t0 full -> buf0; t1's B0,A0,B1 -> buf1 (A1 staged at P1).
    stageB(0, 0, 0); stageA(0, 0, 0); stageB(0, 1, 0); stageA(0, 1, 0);
    stageB(1, 0, 1); stageA(1, 0, 1); stageB(1, 1, 1);
    waitv<0>();
    FENCE; __builtin_amdgcn_s_barrier(); FENCE;
    LDAF(af, 0, 0) LDBF(bqA, 0, 0)

    for (int it = 0; it < NI; ++it) {
        const int t1  = 2 * it + 1;
        const int t0n = 2 * it + 2;
        const int t1n = 2 * it + 3;
        const bool last = (it == NI - 1);

        // P1: Q(0,0) buf0
        PH_ENTRY; MFQ(af, bqA, 0, 0)
        LDBF(bqB, 1, 0)
        stageA(1, 1, t1);
        // P2: Q(0,1) buf0
        PH_ENTRY; MFQ(af, bqB, 0, 1)
        LDAF(af, 1, 0)
        if (!last) stageB(0, 0, t0n);
        // P3: Q(1,1) buf0
        PH_ENTRY; MFQ(af, bqB, 1, 1)
        if (!last) stageA(0, 0, t0n);
        // P4: Q(1,0) buf0 -> buffer switch pre-read
        PH_ENTRY; MFQ(af, bqA, 1, 0)
        if (!last) stageB(0, 1, t0n);
        if (last) { waitv<0>(); } else { waitv<2>(); }
        LDAF(af, 0, 1) LDBF(bqA, 0, 1)
        // P5: Q(0,0) buf1
        PH_ENTRY; MFQ(af, bqA, 0, 0)
        LDBF(bqB, 1, 1)
        if (!last) stageA(0, 1, t0n);
        // P6: Q(0,1) buf1
        PH_ENTRY; MFQ(af, bqB, 0, 1)
        LDAF(af, 1, 1)
        if (!last) stageB(1, 0, t1n);
        // P7: Q(1,1) buf1
        PH_ENTRY; MFQ(af, bqB, 1, 1)
        if (!last) stageA(1, 0, t1n);
        // P8: Q(1,0) buf1 -> buffer switch pre-read (skip on last)
        PH_ENTRY; MFQ(af, bqA, 1, 0)
        if (!last) {
            stageB(1, 1, t1n);
            waitv<2>();
            LDAF(af, 0, 0) LDBF(bqA, 0, 0)
        }
    }
#undef LDAF
#undef LDBF
#undef MFQ
#undef PH_ENTRY

    // epilogue: D layout col=lane&15, row=(lane>>4)*4+r
    const int er = (lane >> 4) * 4;
    const int ec = lane & 15;
    #pragma unroll
    for (int i = 0; i < MR; ++i) {
        #pragma unroll
        for (int j = 0; j < 4; ++j) {
            #pragma unroll
            for (int r = 0; r < 4; ++r) {
                const int row = brow + wm * (BM / 2) + i * 16 + er + r;
                const int col = bcol + wn * 64 + j * 16 + ec;
                const float va = acc[i][j][r];
                if (MODE == 5) {
                    if (col < 2048)
                        ((u16*)Cout)[(size_t)row * 2048 + col] = f2bf(va * scale);
                    else
                        ((u16*)aux)[(size_t)row * 2048 + (col - 2048)] = f2bf(va);
                } else {
                    const size_t idx = (size_t)row * N + col;
                    if (MODE == 0)      ((u16*)Cout)[idx] = f2bf(va);
                    else if (MODE == 1) ((u16*)Cout)[idx] = f2bf(va * scale);
                    else if (MODE == 2) ((float*)Cout)[idx] = resid[idx] + va;
                    else {
                        const float g  = bf2f(aux[idx]);
                        const float sg = g / (1.0f + exp2f(-g * 1.4426950408889634f));
                        ((u16*)Cout)[idx] = f2bf(sg * va);
                    }
                }
            }
        }
    }
}

// ---------------------------------------------------------------------------
// Flash attention fwd (R9/R10 structure): 4 waves x 32 q-rows = 128
// q-rows/block, 512 blocks = 2 blocks/CU; T12 swapped-QK^T in-register
// softmax, T13 defer-max, T14 async-stage, XOR-swizzled K/V dbuf.
// q,k,o: [b][t][h*128+d] bf16.  v PRE-TRANSPOSED: [h*128+d][b*2048+t].
// ---------------------------------------------------------------------------
__global__ __launch_bounds__(256, 2)
void flash_attn(const u16* __restrict__ q, const u16* __restrict__ k,
                const u16* __restrict__ vT, u16* __restrict__ o)
{
    __shared__ __align__(16) u16 Kt[2][64 * 128];
    __shared__ __align__(16) u16 Vt[2][128 * 64];
    const int tid  = threadIdx.x;
    const int lane = tid & 63;
    const int w    = tid >> 6;
    const int qtile = blockIdx.x;
    const int bh    = blockIdx.y;
    const int b = bh >> 4, h = bh & 15;
    const size_t head  = ((size_t)b * 2048) * 2048 + (size_t)h * 128;
    const size_t vbase = ((size_t)h * 128) * 4096 + (size_t)b * 2048;

    s16x8 qf[2][4];
    #pragma unroll
    for (int qi = 0; qi < 2; ++qi) {
        const int tq = qtile * 128 + w * 32 + qi * 16 + (lane & 15);
        const u16* qp = q + head + (size_t)tq * 2048 + (lane >> 4) * 8;
        #pragma unroll
        for (int dk = 0; dk < 4; ++dk) qf[qi][dk] = *(const s16x8*)(qp + dk * 32);
    }

    f32x4 oa[2][8] = {};
    float m_r[2] = {-1e30f, -1e30f};
    float l_r[2] = {0.f, 0.f};

    const int krow = tid >> 2;
    const int kc0  = (tid & 3) * 32;
    const int vd   = tid >> 1;
    const int vk0  = (tid & 1) * 32;
    const u16* kg = k + head + (size_t)krow * 2048 + kc0;
    const u16* vg = vT + vbase + (size_t)vd * 4096 + vk0;
    u32 kwo[4], vwo[4];
    #pragma unroll
    for (int c = 0; c < 4; ++c) {
        kwo[c] = (u32)((krow * 256 + (kc0 + c * 8) * 2) ^ ((krow & 7) << 4));
        vwo[c] = (u32)((vd * 128 + (vk0 + c * 8) * 2)   ^ ((vd & 7) << 4));
    }

    s16x8 kr[4], vr[4];
    #pragma unroll
    for (int c = 0; c < 4; ++c) {
        kr[c] = *(const s16x8*)(kg + c * 8);
        vr[c] = *(const s16x8*)(vg + c * 8);
    }

    for (int kb = 0; kb < 32; ++kb) {
        const int cur = kb & 1;
        char* KtB = (char*)&Kt[cur][0];
        char* VtB = (char*)&Vt[cur][0];
        #pragma unroll
        for (int c = 0; c < 4; ++c) {
            *(s16x8*)(KtB + kwo[c]) = kr[c];
            *(s16x8*)(VtB + vwo[c]) = vr[c];
        }
        if (kb + 1 < 32) {
            const int k0n = (kb + 1) * 64;
            #pragma unroll
            for (int c = 0; c < 4; ++c) {
                kr[c] = *(const s16x8*)(kg + (size_t)k0n * 2048 + c * 8);
                vr[c] = *(const s16x8*)(vg + k0n + c * 8);
            }
        }
        asm volatile("s_waitcnt lgkmcnt(0)" ::: "memory");
        __builtin_amdgcn_s_barrier();
        FENCE;

        f32x4 st[2][4] = {};
        __builtin_amdgcn_s_setprio(1);
        #pragma unroll
        for (int kt = 0; kt < 4; ++kt) {
            const int row = kt * 16 + (lane & 15);
            s16x8 kf[4];
            #pragma unroll
            for (int dk = 0; dk < 4; ++dk) {
                const int dcol = dk * 32 + (lane >> 4) * 8;
                kf[dk] = *(const s16x8*)(KtB + ((row * 256 + dcol * 2) ^ ((row & 7) << 4)));
            }
            #pragma unroll
            for (int qi = 0; qi < 2; ++qi)
                #pragma unroll
                for (int dk = 0; dk < 4; ++dk)
                    st[qi][kt] = __builtin_amdgcn_mfma_f32_16x16x32_bf16(kf[dk], qf[qi][dk], st[qi][kt], 0, 0, 0);
        }
        __builtin_amdgcn_s_setprio(0);

        float mx[2];
        #pragma unroll
        for (int qi = 0; qi < 2; ++qi) {
            float m0 = fmaxf(fmaxf(st[qi][0][0], st[qi][0][1]), fmaxf(st[qi][0][2], st[qi][0][3]));
            float m1 = fmaxf(fmaxf(st[qi][1][0], st[qi][1][1]), fmaxf(st[qi][1][2], st[qi][1][3]));
            float m2 = fmaxf(fmaxf(st[qi][2][0], st[qi][2][1]), fmaxf(st[qi][2][2], st[qi][2][3]));
            float m3 = fmaxf(fmaxf(st[qi][3][0], st[qi][3][1]), fmaxf(st[qi][3][2], st[qi][3][3]));
            float m0123 = fmaxf(fmaxf(m0, m1), fmaxf(m2, m3));
            m0123 = fmaxf(m0123, __shfl_xor(m0123, 16));
            m0123 = fmaxf(m0123, __shfl_xor(m0123, 32));
            mx[qi] = m0123;
        }
        const bool grow = (mx[0] > m_r[0] + 8.f) || (mx[1] > m_r[1] + 8.f);
        if (__any(grow)) {
            #pragma unroll
            for (int qi = 0; qi < 2; ++qi) {
                const float mn = fmaxf(m_r[qi], mx[qi]);
                const float sc = exp2f(m_r[qi] - mn);
                m_r[qi] = mn;
                l_r[qi] *= sc;
                const float s0 = __shfl(sc, (lane >> 4) * 4 + 0);
                const float s1 = __shfl(sc, (lane >> 4) * 4 + 1);
                const float s2 = __shfl(sc, (lane >> 4) * 4 + 2);
                const float s3 = __shfl(sc, (lane >> 4) * 4 + 3);
                #pragma unroll
                for (int ni = 0; ni < 8; ++ni) {
                    oa[qi][ni][0] *= s0; oa[qi][ni][1] *= s1;
                    oa[qi][ni][2] *= s2; oa[qi][ni][3] *= s3;
                }
            }
        }

        s16x8 pa[2][2];
        #pragma unroll
        for (int qi = 0; qi < 2; ++qi) {
            float sum = 0.f;
            #pragma unroll
            for (int kt = 0; kt < 4; ++kt)
                #pragma unroll
                for (int r = 0; r < 4; ++r) {
                    const float p = exp2f(st[qi][kt][r] - m_r[qi]);
                    st[qi][kt][r] = p;
                    sum += p;
                }
            sum += __shfl_xor(sum, 16);
            sum += __shfl_xor(sum, 32);
            l_r[qi] += sum;

            u32 q01[4], q23[4];
            #pragma unroll
            for (int kt = 0; kt < 4; ++kt) {
                q01[kt] = cvtpk(st[qi][kt][0], st[qi][kt][1]);
                q23[kt] = cvtpk(st[qi][kt][2], st[qi][kt][3]);
            }
            #pragma unroll
            for (int ks = 0; ks < 2; ++ks) {
                u32 X = q01[2 * ks], Y = q01[2 * ks + 1];
                swap32(X, Y); swap16(X, Y);
                u32 U = q23[2 * ks], V = q23[2 * ks + 1];
                swap32(U, V); swap16(U, V);
                u32x4 t; t[0] = X; t[1] = U; t[2] = Y; t[3] = V;
                pa[qi][ks] = __builtin_bit_cast(s16x8, t);
            }
        }

        __builtin_amdgcn_s_setprio(1);
        #pragma unroll
        for (int ks = 0; ks < 2; ++ks) {
            const int keyb = ks * 32 + (lane >> 4) * 8;
            #pragma unroll
            for (int ni = 0; ni < 8; ++ni) {
                const int dd = ni * 16 + (lane & 15);
                s16x8 vf = *(const s16x8*)(VtB + ((dd * 128 + keyb * 2) ^ ((dd & 7) << 4)));
                #pragma unroll
                for (int qi = 0; qi < 2; ++qi)
                    oa[qi][ni] = __builtin_amdgcn_mfma_f32_16x16x32_bf16(pa[qi][ks], vf, oa[qi][ni], 0, 0, 0);
            }
        }
        __builtin_amdgcn_s_setprio(0);
    }
    #pragma unroll
    for (int qi = 0; qi < 2; ++qi) {
        #pragma unroll
        for (int r = 0; r < 4; ++r) {
            const float inv = 1.0f / __shfl(l_r[qi], (lane >> 4) * 4 + r);
            const int tout = qtile * 128 + w * 32 + qi * 16 + (lane >> 4) * 4 + r;
            u16* op = o + head + (size_t)tout * 2048 + (lane & 15);
            #pragma unroll
            for (int ni = 0; ni < 8; ++ni)
                op[ni * 16] = f2bf(oa[qi][ni][r] * inv);
        }
    }
}

// ---------------------------------------------------------------------------
extern "C" void kernel_launch(void* const* d_in, const int* in_sizes, int n_in,
                              void* d_out, int out_size, void* d_ws, size_t ws_size,
                              hipStream_t stream)
{
    (void)in_sizes; (void)n_in; (void)out_size; (void)ws_size;
    const float* x    = (const float*)d_in[0];
    const float* wln1 = (const float*)d_in[1];
    const float* wq   = (const float*)d_in[2];
    const float* wk   = (const float*)d_in[3];
    const float* wv   = (const float*)d_in[4];
    const float* wo   = (const float*)d_in[5];
    const float* wln2 = (const float*)d_in[6];
    const float* wg   = (const float*)d_in[7];
    const float* wu   = (const float*)d_in[8];
    const float* wd   = (const float*)d_in[9];
    float* out = (float*)d_out;

    const size_t MB = 1024ull * 1024ull;
    char* ws = (char*)d_ws;
    u16*   arena = (u16*)(ws + 0);          // 32 MB: bf16 weight arena (reused)
    float* hbuf  = (float*)(ws + 32 * MB);  // 32 MB: x + attn residual (fp32)
    u16*   xn    = (u16*)(ws + 64 * MB);    // 16 MB: rmsnorm output (bf16)
    u16*   qb    = (u16*)(ws + 80 * MB);    // 16 MB
    u16*   kbuf  = (u16*)(ws + 96 * MB);    // 16 MB
    u16*   vT    = (u16*)(ws + 112 * MB);   // 16 MB: V transposed [h*128+d][b*2048+t]
    u16*   abuf  = (u16*)(ws + 128 * MB);   // 16 MB (ends 144 MB)
    u16*   gbuf  = (u16*)(ws + 80 * MB);    // 64 MB, aliases q..attn (dead then)

    const int M = 4096, C = 2048, I = 8192;
    const float qscale = 0.1275164899f;     // (1/sqrt(128)) * log2(e)
    dim3 blk(256);
    dim3 blk8(512);

    rmsnorm_k<<<M, blk, 0, stream>>>(x, wln1, xn, C);

    // fused Q+K: arena = [wq ; wk] (4096 x 2048), one gemm8 with split epilogue
    cast_w<<<(C * C) / 2048, blk, 0, stream>>>(wq, arena, C * C);
    cast_w<<<(C * C) / 2048, blk, 0, stream>>>(wk, arena + (size_t)C * C, C * C);
    gemm8<5, 4><<<dim3((2 * C / 256) * (M / 128)), blk8, 0, stream>>>(
        xn, arena, nullptr, kbuf, qb, M, 2 * C, C, qscale);

    cast_w<<<(C * C) / 2048, blk, 0, stream>>>(wv, arena, C * C);
    // V^T = Wv @ Xn^T : operand-swapped GEMM -> coalesced transposed output
    gemm8<0, 4><<<dim3((M / 256) * (C / 128)), blk8, 0, stream>>>(arena, xn, nullptr, nullptr, vT, C, M, C, 1.f);

    flash_attn<<<dim3(2048 / 128, 32), blk, 0, stream>>>(qb, kbuf, vT, abuf);

    cast_w<<<(C * C) / 2048, blk, 0, stream>>>(wo, arena, C * C);
    gemm8<2, 4><<<dim3((C / 256) * (M / 128)), blk8, 0, stream>>>(abuf, arena, x, nullptr, hbuf, M, C, C, 1.f);

    rmsnorm_k<<<M, blk, 0, stream>>>(hbuf, wln2, xn, C);

    cast_w<<<(I * C) / 2048, blk, 0, stream>>>(wg, arena, I * C);
    gemm8<0, 8><<<dim3((I / 256) * (M / 256)), blk8, 0, stream>>>(xn, arena, nullptr, nullptr, gbuf, M, I, C, 1.f);
    cast_w<<<(I * C) / 2048, blk, 0, stream>>>(wu, arena, I * C);
    gemm8<3, 8><<<dim3((I / 256) * (M / 256)), blk8, 0, stream>>>(xn, arena, nullptr, gbuf, gbuf, M, I, C, 1.f);
    cast_w<<<(C * I) / 2048, blk, 0, stream>>>(wd, arena, C * I);
    gemm8<2, 4><<<dim3((C / 256) * (M / 128)), blk8, 0, stream>>>(gbuf, arena, hbuf, nullptr, out, M, C, I, 1.f);
}